// Round 8
// baseline (5211.177 us; speedup 1.0000x reference)
//
#include <hip/hip_runtime.h>
#include <stdint.h>
#include <float.h>

typedef unsigned int uint;

#define NB 8
#define NPTS 4096
#define NS 512
#define NKN 32

// ---- static device scratch (~177 MB, allocated at module load; fully rewritten each call)
__device__ int   g_fps_idx[NB*NS];
__device__ int   g_knn_idx[NB*NS*NKN];
__device__ float g_knn_d2 [NB*NS*NKN];
__device__ float g_posb   [(size_t)NB*NS*NKN*64];    //  33.5 MB
__device__ float g_ga     [(size_t)NB*NS*NS];        //   8.4 MB
__device__ float g_dsa    [(size_t)NB*NS*NKN*256];   // 134 MB  [group*32+k][256] = [nei|grp]

__device__ __forceinline__ unsigned long long shfl_down_u64(unsigned long long v, int off){
  int lo = __shfl_down((int)(unsigned)v, off);
  int hi = __shfl_down((int)(unsigned)(v >> 32), off);
  return ((unsigned long long)(unsigned)hi << 32) | (unsigned)lo;
}
__device__ __forceinline__ unsigned long long u64max(unsigned long long a, unsigned long long b){
  return a > b ? a : b;
}
__device__ __forceinline__ unsigned long long u64min(unsigned long long a, unsigned long long b){
  return a < b ? a : b;
}
__device__ __forceinline__ void ldf8(const float* p, float* d){
  float4 a = *(const float4*)p, b = *(const float4*)(p+4);
  d[0]=a.x; d[1]=a.y; d[2]=a.z; d[3]=a.w; d[4]=b.x; d[5]=b.y; d[6]=b.z; d[7]=b.w;
}
// robust start read: int32 (start[b]) vs int64 (start[2b]; high words zero since values<4096)
__device__ __forceinline__ int read_start(const int* __restrict__ start, int b){
  int w1 = start[1], w3 = start[3], w5 = start[5], w7 = start[7];
  bool is64 = ((w1 | w3 | w5 | w7) == 0);
  int v = is64 ? start[2*b] : start[b];
  return v & (NPTS - 1);
}

// flat column order: n = k*128 + d, d<64 -> posb, d>=64 -> points gather
__device__ __forceinline__ void load_flat8(const float* __restrict__ points,
                                           int b, int row, int n, float* d){
  const int k = n >> 7, col = n & 63;
  if (n & 64){
    const int idx = g_knn_idx[((b << 9) + row)*32 + k];
    ldf8(points + (((size_t)b << 12) + idx)*64 + col, d);
  } else {
    ldf8(g_posb + (((size_t)((b << 9) + row))*32 + k)*64 + col, d);
  }
}
__device__ __forceinline__ float4 load_flat4(const float* __restrict__ points,
                                             int b, int row, int n){
  const int k = n >> 7, d = n & 127;
  if (d & 64){
    const int idx = g_knn_idx[((b << 9) + row)*32 + k];
    return *(const float4*)(points + (((size_t)b << 12) + idx)*64 + (d & 63));
  } else {
    return *(const float4*)(g_posb + (((size_t)((b << 9) + row))*32 + k)*64 + d);
  }
}
// reorganized order for Gram only: kc in [0,2048) pos (k-major), [2048,4096) pts
__device__ __forceinline__ void load_gram8(const float* __restrict__ points,
                                           int b, int row, int kc, float* d){
  if (kc < 2048){
    ldf8(g_posb + ((size_t)((b << 9) + row))*2048 + kc, d);
  } else {
    const int kc2 = kc - 2048, kg = kc2 >> 6, col = kc2 & 63;
    const int idx = g_knn_idx[((b << 9) + row)*32 + kg];
    ldf8(points + (((size_t)b << 12) + idx)*64 + col, d);
  }
}

// ---------------------------------------------------------------- FPS (f32 packed-key selection, 256 thr)
__global__ __launch_bounds__(256) void k_fps(const float* __restrict__ xyz,
                                             const int* __restrict__ start,
                                             float* __restrict__ center_out){
#pragma clang fp contract(off)
  const int b = blockIdx.x, tid = threadIdx.x;
  const float* X = xyz + (size_t)b * NPTS * 3;
  __shared__ float sx[NPTS], sy[NPTS], sz[NPTS];
  for (int p = tid; p < NPTS; p += 256){
    sx[p] = X[3*p]; sy[p] = X[3*p+1]; sz[p] = X[3*p+2];
  }
  __shared__ int s_start0;
  if (tid == 0) s_start0 = read_start(start, b);
  __syncthreads();
  float px[16], py[16], pz[16], dist[16];
  for (int i = 0; i < 16; i++){
    int p = tid*16 + i;
    px[i] = sx[p]; py[i] = sy[p]; pz[i] = sz[p];
    dist[i] = 1e10f;
  }
  __shared__ unsigned long long s_k[2][4];
  int cur = s_start0;
  for (int t = 0; t < NS; t++){
    if (tid == 0){
      g_fps_idx[b*NS + t] = cur;
      center_out[(size_t)(b*NS + t)*3 + 0] = sx[cur];
      center_out[(size_t)(b*NS + t)*3 + 1] = sy[cur];
      center_out[(size_t)(b*NS + t)*3 + 2] = sz[cur];
    }
    const float cx = sx[cur], cy = sy[cur], cz = sz[cur];
    unsigned long long k_[16];
#pragma unroll
    for (int i = 0; i < 16; i++){
      float dx = px[i]-cx, dy = py[i]-cy, dz = pz[i]-cz;
      float d = ((dx*dx) + (dy*dy)) + (dz*dz);
      dist[i] = fminf(dist[i], d);
      k_[i] = ((unsigned long long)__float_as_uint(dist[i]) << 32)
            | (unsigned)(NPTS-1 - (tid*16 + i));
    }
#pragma unroll
    for (int st = 8; st; st >>= 1)
      for (int i = 0; i < st; i++) k_[i] = u64max(k_[i], k_[i+st]);
    unsigned long long bk = k_[0];
    { unsigned long long a = shfl_down_u64(bk,16), c = shfl_down_u64(bk,32), d = shfl_down_u64(bk,48);
      bk = u64max(u64max(bk,a), u64max(c,d)); }
    { unsigned long long a = shfl_down_u64(bk,4),  c = shfl_down_u64(bk,8),  d = shfl_down_u64(bk,12);
      bk = u64max(u64max(bk,a), u64max(c,d)); }
    { unsigned long long a = shfl_down_u64(bk,1),  c = shfl_down_u64(bk,2),  d = shfl_down_u64(bk,3);
      bk = u64max(u64max(bk,a), u64max(c,d)); }
    const int par = t & 1;
    if ((tid & 63) == 0) s_k[par][tid>>6] = bk;
    __syncthreads();
    unsigned long long m = u64max(u64max(s_k[par][0], s_k[par][1]),
                                  u64max(s_k[par][2], s_k[par][3]));
    cur = NPTS-1 - (int)(unsigned)m;
  }
}

// ---------------------------------------------------------------- KNN top-32 (f32 packed-key, 1 barrier/sel)
__global__ __launch_bounds__(256) void k_knn(const float* __restrict__ xyz){
#pragma clang fp contract(off)
  const int g = blockIdx.x;            // b*512 + s
  const int b = g >> 9;
  const int tid = threadIdx.x;
  const float* X = xyz + (size_t)b * NPTS * 3;
  const int cidx = g_fps_idx[g];
  const float cx = X[3*cidx], cy = X[3*cidx+1], cz = X[3*cidx+2];
  const float cs = ((cx*cx) + (cy*cy)) + (cz*cz);
  unsigned long long kl[16];
#pragma unroll
  for (int i = 0; i < 16; i++){
    int p = tid*16 + i;
    float x = X[3*p], y = X[3*p+1], z = X[3*p+2];
    float xs2 = ((x*x) + (y*y)) + (z*z);
    float dt  = ((cx*x) + (cy*y)) + (cz*z);
    float d   = (cs + xs2) - 2.0f*dt;
    unsigned bits = __float_as_uint(d);
    unsigned mono = (bits & 0x80000000u) ? ~bits : (bits ^ 0x80000000u);
    kl[i] = ((unsigned long long)mono << 32) | (unsigned)p;
  }
  __shared__ unsigned long long s_w[2][4];
  unsigned long long last = 0;
  for (int sel = 0; sel < NKN; sel++){
    unsigned long long mk[16];
#pragma unroll
    for (int i = 0; i < 16; i++)
      mk[i] = (kl[i] > last) ? kl[i] : 0xFFFFFFFFFFFFFFFFULL;
#pragma unroll
    for (int st = 8; st; st >>= 1)
      for (int i = 0; i < st; i++) mk[i] = u64min(mk[i], mk[i+st]);
    unsigned long long bk = mk[0];
    { unsigned long long a = shfl_down_u64(bk,16), c = shfl_down_u64(bk,32), d = shfl_down_u64(bk,48);
      bk = u64min(u64min(bk,a), u64min(c,d)); }
    { unsigned long long a = shfl_down_u64(bk,4),  c = shfl_down_u64(bk,8),  d = shfl_down_u64(bk,12);
      bk = u64min(u64min(bk,a), u64min(c,d)); }
    { unsigned long long a = shfl_down_u64(bk,1),  c = shfl_down_u64(bk,2),  d = shfl_down_u64(bk,3);
      bk = u64min(u64min(bk,a), u64min(c,d)); }
    const int par = sel & 1;
    if ((tid & 63) == 0) s_w[par][tid>>6] = bk;
    __syncthreads();
    unsigned long long m = u64min(u64min(s_w[par][0], s_w[par][1]),
                                  u64min(s_w[par][2], s_w[par][3]));
    last = m;
    if (tid == 0){
      unsigned hm = (unsigned)(m >> 32);
      unsigned bits = (hm & 0x80000000u) ? (hm ^ 0x80000000u) : ~hm;
      g_knn_idx[g*NKN + sel] = (int)(unsigned)m;
      g_knn_d2 [g*NKN + sel] = __uint_as_float(bits);
    }
  }
}

// ---------------------------------------------------------------- pos-embed MLP -> g_posb (f32)
__global__ __launch_bounds__(256) void k_posembed(
    const float* __restrict__ xyz,
    const float* __restrict__ w1, const float* __restrict__ b1, const float* __restrict__ bn1,
    const float* __restrict__ w2, const float* __restrict__ b2, const float* __restrict__ bn2){
  __shared__ float w1s[320], a1s[32], d1s[32], w2s[2048], a2s[64], d2s[64];
  const int t = threadIdx.x;
  for (int i = t; i < 320; i += 256) w1s[i] = w1[i];
  for (int i = t; i < 2048; i += 256) w2s[i] = w2[i];
  if (t < 32){
    float g = bn1[t], be = bn1[32+t], m = bn1[64+t], v = bn1[96+t];
    float a = g * rsqrtf(v + 1e-5f);
    a1s[t] = a; d1s[t] = b1[t]*a + (be - m*a);
  }
  if (t < 64){
    float g = bn2[t], be = bn2[64+t], m = bn2[128+t], v = bn2[192+t];
    float a = g * rsqrtf(v + 1e-5f);
    a2s[t] = a; d2s[t] = b2[t]*a + (be - m*a);
  }
  __syncthreads();
  const int row = blockIdx.x*256 + t;          // (b*512+s)*32 + k
  const int b = row >> 14;
  const int g = row >> 5;
  const float* X = xyz + (size_t)b * NPTS * 3;
  const int ci = g_fps_idx[g];
  const int ni = g_knn_idx[row];
  float c0 = X[3*ci], c1 = X[3*ci+1], c2 = X[3*ci+2];
  float n0 = X[3*ni], n1 = X[3*ni+1], n2 = X[3*ni+2];
  float feat[10] = {c0,c1,c2, n0,n1,n2, n0-c0,n1-c1,n2-c2, g_knn_d2[row]};
  float h[32];
  for (int o = 0; o < 32; o++){
    float acc = 0.f;
    for (int j = 0; j < 10; j++) acc += feat[j]*w1s[j*32+o];
    h[o] = fmaxf(acc*a1s[o] + d1s[o], 0.f);
  }
  float* xr = g_posb + (size_t)row * 64;
  for (int o = 0; o < 64; o++){
    float acc = 0.f;
    for (int j = 0; j < 32; j++) acc += h[j]*w2s[j*64+o];
    xr[o] = fmaxf(acc*a2s[o] + d2s[o], 0.f);
  }
}

// ---------------------------------------------------------------- Gram = flat @ flat^T (f32, symmetric)
__global__ __launch_bounds__(256) void k_gram(const float* __restrict__ points){
  const int b = blockIdx.y;
  int ti = 0, rem = blockIdx.x;
  while (rem >= 8 - ti){ rem -= 8 - ti; ti++; }
  const int tj = ti + rem;
  const int i0 = ti * 64, j0 = tj * 64;
  __shared__ float As[32][68];
  __shared__ float Bs[32][68];
  const int t = threadIdx.x, tx = t & 15, ty = t >> 4;
  float acc[4][4] = {};
  for (int k0 = 0; k0 < 4096; k0 += 32){
    {
      int r = t >> 2, kk = (t & 3) * 8;
      float ta[8], tb[8];
      load_gram8(points, b, i0+r, k0+kk, ta);
      load_gram8(points, b, j0+r, k0+kk, tb);
      for (int jj = 0; jj < 8; jj++){
        int k = kk + jj;
        int c = (r + (k & 24)) & 63;   // rotated column, conflict-free store
        As[k][c] = ta[jj]; Bs[k][c] = tb[jj];
      }
    }
    __syncthreads();
    for (int kk = 0; kk < 32; kk++){
      const int rot = kk & 24;
      const float4 a4 = *(const float4*)(&As[kk][(ty*4 + rot) & 63]);
      const float4 b4 = *(const float4*)(&Bs[kk][(tx*4 + rot) & 63]);
      const float ar[4] = {a4.x,a4.y,a4.z,a4.w};
      const float br[4] = {b4.x,b4.y,b4.z,b4.w};
      for (int ia = 0; ia < 4; ia++)
        for (int ib = 0; ib < 4; ib++) acc[ia][ib] += ar[ia]*br[ib];
    }
    __syncthreads();
  }
  float* C = g_ga + (size_t)b * NS * NS;
  for (int ia = 0; ia < 4; ia++){
    float4 o = {acc[ia][0], acc[ia][1], acc[ia][2], acc[ia][3]};
    *(float4*)(C + (size_t)(i0+ty*4+ia)*NS + j0 + tx*4) = o;
  }
  if (ti != tj){
    for (int ib = 0; ib < 4; ib++){
      float4 o = {acc[0][ib], acc[1][ib], acc[2][ib], acc[3][ib]};
      *(float4*)(C + (size_t)(j0+tx*4+ib)*NS + i0 + ty*4) = o;
    }
  }
}

// ---------------------------------------------------------------- row softmax (in place)
__global__ __launch_bounds__(256) void k_softmax(){
  float* R = g_ga + (size_t)blockIdx.x * NS;
  const int t = threadIdx.x;
  float v0 = R[t], v1 = R[t+256];
  __shared__ float sm[4], ssum[4];
  float m = fmaxf(v0, v1);
  for (int off = 32; off; off >>= 1) m = fmaxf(m, __shfl_down(m, off));
  if ((t & 63) == 0) sm[t>>6] = m;
  __syncthreads();
  float mm = fmaxf(fmaxf(sm[0], sm[1]), fmaxf(sm[2], sm[3]));
  float e0 = expf(v0 - mm), e1 = expf(v1 - mm);
  float s = e0 + e1;
  for (int off = 32; off; off >>= 1) s += __shfl_down(s, off);
  if ((t & 63) == 0) ssum[t>>6] = s;
  __syncthreads();
  float inv = 1.0f / (ssum[0]+ssum[1]+ssum[2]+ssum[3]);
  R[t] = e0*inv; R[t+256] = e1*inv;
}

// ---------------------------------------------------------------- grp: ga @ flat, fused gamma*+x -> g_dsa[...,128:256]
__global__ __launch_bounds__(256) void k_grp(const float* __restrict__ points,
                                             const float* __restrict__ gam_g){
  const int b = blockIdx.y;
  const int s0 = (blockIdx.x >> 6) * 64, n0 = (blockIdx.x & 63) * 64;
  const float* G = g_ga + (size_t)b * NS * NS;
  __shared__ float As[32][68];
  __shared__ float Bs[32][68];
  const int t = threadIdx.x, tx = t & 15, ty = t >> 4;
  float acc[4][4] = {};
  for (int k0 = 0; k0 < NS; k0 += 32){
    {
      int r = t >> 2, kk = (t & 3) * 8;
      const float* pa = G + (size_t)(s0+r)*NS + k0 + kk;
      float4 v0 = *(const float4*)pa, v1 = *(const float4*)(pa+4);
      const float va[8] = {v0.x,v0.y,v0.z,v0.w,v1.x,v1.y,v1.z,v1.w};
      for (int jj = 0; jj < 8; jj++){
        int k = kk + jj;
        As[k][(r + (k & 24)) & 63] = va[jj];   // rotated column, conflict-free store
      }
      int k2 = t >> 3, c = (t & 7) * 8;
      float tb[8];
      load_flat8(points, b, k0+k2, n0+c, tb);
      float4 w0 = {tb[0],tb[1],tb[2],tb[3]}, w1 = {tb[4],tb[5],tb[6],tb[7]};
      *(float4*)(&Bs[k2][c])   = w0;
      *(float4*)(&Bs[k2][c+4]) = w1;
    }
    __syncthreads();
    for (int kk = 0; kk < 32; kk++){
      const float4 a4 = *(const float4*)(&As[kk][(ty*4 + (kk & 24)) & 63]);
      const float4 b4 = *(const float4*)(&Bs[kk][tx*4]);
      const float ar[4] = {a4.x,a4.y,a4.z,a4.w};
      const float br[4] = {b4.x,b4.y,b4.z,b4.w};
      for (int ia = 0; ia < 4; ia++)
        for (int ib = 0; ib < 4; ib++) acc[ia][ib] += ar[ia]*br[ib];
    }
    __syncthreads();
  }
  const float gmg = gam_g[0];
  const int n = n0 + tx*4;
  const int kq = n >> 7, dq = n & 127;
  for (int ia = 0; ia < 4; ia++){
    int s = s0 + ty*4 + ia;
    float4 xv = load_flat4(points, b, s, n);
    float4 o = {gmg*acc[ia][0]+xv.x, gmg*acc[ia][1]+xv.y,
                gmg*acc[ia][2]+xv.z, gmg*acc[ia][3]+xv.w};
    *(float4*)(g_dsa + ((size_t)((b*NS + s)*32 + kq))*256 + 128 + dq) = o;
  }
}

// ---------------------------------------------------------------- NSA: Q/K/V + softmax + PV -> g_dsa[...,0:128]
// Weight matrices staged in LDS: wq/wk fully (8KB each), wv in four 32-row tiles
// (16KB buffer, reused). Eliminates the 32x per-block weight re-streaming
// (~2.3MB -> ~80KB VMEM per block; aggregate was ~28 TB/s, at the L2 ceiling).
// V accumulation held in registers across tiles, j ascending -> bit-exact.
__global__ __launch_bounds__(256) void k_nsa(const float* __restrict__ points,
    const float* __restrict__ wq, const float* __restrict__ bq,
    const float* __restrict__ wk, const float* __restrict__ bk,
    const float* __restrict__ wv, const float* __restrict__ bv_,
    const float* __restrict__ nsa_g){
  const int g = blockIdx.y*512 + blockIdx.x;
  const int t = threadIdx.x, b = g >> 9;
  const int r = t >> 3, c = t & 7;
  __shared__ float xs[32][132];
  __shared__ float vs[32][132];          // float4 view: row stride 33
  __shared__ float qs[32][17], ks[32][17];
  __shared__ float at[32][33];
  __shared__ float wqs[2048];            // 128x16
  __shared__ float wks[2048];            // 128x16
  __shared__ float wvs[4096];            // 32x128 tile (reused 4x)
  // stage x row r (8 lanes of subgroup r cover the row) + wq/wk
  {
    float tmp[8];
    ldf8(g_posb + ((size_t)g*32 + r)*64 + c*8, tmp);
    for (int j = 0; j < 8; j++) xs[r][c*8+j] = tmp[j];
    int idx = g_knn_idx[g*32 + r];
    ldf8(points + ((size_t)b*NPTS + idx)*64 + c*8, tmp);
    for (int j = 0; j < 8; j++) xs[r][64+c*8+j] = tmp[j];
  }
  for (int i = t; i < 512; i += 256){
    ((float4*)wqs)[i] = ((const float4*)wq)[i];
    ((float4*)wks)[i] = ((const float4*)wk)[i];
  }
  __syncthreads();
  // Q/K projections from LDS (thread computes q[r][c], q[r][c+8], k[r][c], k[r][c+8])
  {
    float aq0 = bq[c], aq1 = bq[c+8], ak0 = bk[c], ak1 = bk[c+8];
    for (int j = 0; j < 128; j++){
      float xv = xs[r][j];
      aq0 += xv * wqs[j*16+c];
      aq1 += xv * wqs[j*16+c+8];
      ak0 += xv * wks[j*16+c];
      ak1 += xv * wks[j*16+c+8];
    }
    qs[r][c] = aq0; qs[r][c+8] = aq1; ks[r][c] = ak0; ks[r][c+8] = ak1;
  }
  // V projection, channels d = 32w + 4c + ii; wv streamed through LDS in 32-row tiles
  {
    const float4* bv4 = (const float4*)bv_;
    float4 va = bv4[c], vb = bv4[8+c], vc4 = bv4[16+c], vd = bv4[24+c];
    for (int t4 = 0; t4 < 4; t4++){
      if (t4) __syncthreads();           // prior tile's reads complete before overwrite
      for (int i = t; i < 1024; i += 256)
        ((float4*)wvs)[i] = ((const float4*)wv)[(size_t)t4*1024 + i];
      __syncthreads();
      for (int jl = 0; jl < 32; jl++){
        float xv = xs[r][t4*32 + jl];
        const float4* row = (const float4*)(wvs + jl*128);
        float4 w0 = row[c], w1 = row[8+c], w2 = row[16+c], w3 = row[24+c];
        va.x += xv*w0.x;  va.y += xv*w0.y;  va.z += xv*w0.z;  va.w += xv*w0.w;
        vb.x += xv*w1.x;  vb.y += xv*w1.y;  vb.z += xv*w1.z;  vb.w += xv*w1.w;
        vc4.x += xv*w2.x; vc4.y += xv*w2.y; vc4.z += xv*w2.z; vc4.w += xv*w2.w;
        vd.x += xv*w3.x;  vd.y += xv*w3.y;  vd.z += xv*w3.z;  vd.w += xv*w3.w;
      }
    }
    float4* vrow = (float4*)(&vs[r][0]);
    vrow[c] = va; vrow[8+c] = vb; vrow[16+c] = vc4; vrow[24+c] = vd;
  }
  __syncthreads();   // ks / vs cross-wave visibility
  // QK^T: s[jj] = q[r] . k[4c+jj]
  float p0, p1, p2, p3;
  {
    float s[4];
    for (int jj = 0; jj < 4; jj++){
      int j = 4*c + jj; float acc = 0.f;
      for (int cc = 0; cc < 16; cc++) acc += qs[r][cc] * ks[j][cc];
      s[jj] = acc;
    }
    // row softmax across the 8-lane subgroup (all lanes active)
    float m = fmaxf(fmaxf(s[0], s[1]), fmaxf(s[2], s[3]));
    m = fmaxf(m, __shfl_xor(m, 1));
    m = fmaxf(m, __shfl_xor(m, 2));
    m = fmaxf(m, __shfl_xor(m, 4));
    float e0 = expf(s[0]-m), e1 = expf(s[1]-m), e2 = expf(s[2]-m), e3 = expf(s[3]-m);
    float sum = ((e0 + e1) + (e2 + e3));
    sum += __shfl_xor(sum, 1);
    sum += __shfl_xor(sum, 2);
    sum += __shfl_xor(sum, 4);
    float inv = 1.0f / sum;
    p0 = e0*inv; p1 = e1*inv; p2 = e2*inv; p3 = e3*inv;
    at[r][4*c+0] = p0; at[r][4*c+1] = p1; at[r][4*c+2] = p2; at[r][4*c+3] = p3;
  }
  // PV + gamma*.+x residual (at row r is wave-local; vs synced above)
  {
    float4 a0 = {0,0,0,0}, a1 = {0,0,0,0}, a2 = {0,0,0,0}, a3 = {0,0,0,0};
    for (int j = 0; j < 32; j++){
      float a = at[r][j];
      const float4* vrow = (const float4*)(&vs[j][0]);
      float4 w0 = vrow[c], w1 = vrow[8+c], w2 = vrow[16+c], w3 = vrow[24+c];
      a0.x += a*w0.x; a0.y += a*w0.y; a0.z += a*w0.z; a0.w += a*w0.w;
      a1.x += a*w1.x; a1.y += a*w1.y; a1.z += a*w1.z; a1.w += a*w1.w;
      a2.x += a*w2.x; a2.y += a*w2.y; a2.z += a*w2.z; a2.w += a*w2.w;
      a3.x += a*w3.x; a3.y += a*w3.y; a3.z += a*w3.z; a3.w += a*w3.w;
    }
    const float gmn = nsa_g[0];
    float* dst = g_dsa + ((size_t)g*32 + r)*256;
    float4 x0 = *(const float4*)(&xs[r][ 0+4*c]);
    float4 x1 = *(const float4*)(&xs[r][32+4*c]);
    float4 x2 = *(const float4*)(&xs[r][64+4*c]);
    float4 x3 = *(const float4*)(&xs[r][96+4*c]);
    float4 o0 = {gmn*a0.x+x0.x, gmn*a0.y+x0.y, gmn*a0.z+x0.z, gmn*a0.w+x0.w};
    float4 o1 = {gmn*a1.x+x1.x, gmn*a1.y+x1.y, gmn*a1.z+x1.z, gmn*a1.w+x1.w};
    float4 o2 = {gmn*a2.x+x2.x, gmn*a2.y+x2.y, gmn*a2.z+x2.z, gmn*a2.w+x2.w};
    float4 o3 = {gmn*a3.x+x3.x, gmn*a3.y+x3.y, gmn*a3.z+x3.z, gmn*a3.w+x3.w};
    *(float4*)(dst +  0 + 4*c) = o0;
    *(float4*)(dst + 32 + 4*c) = o1;
    *(float4*)(dst + 64 + 4*c) = o2;
    *(float4*)(dst + 96 + 4*c) = o3;
  }
}

// ---------------------------------------------------------------- cat MLP + shortcut + maxpool -> out
// Round-3 structure restored (measured best: 530us). 256 threads, separate hs buffer.
__global__ __launch_bounds__(256) void k_mlp(const float* __restrict__ points,
    const float* __restrict__ w1, const float* __restrict__ b1, const float* __restrict__ bn1,
    const float* __restrict__ w2, const float* __restrict__ b2, const float* __restrict__ bn2,
    const float* __restrict__ wsc, const float* __restrict__ bsc, const float* __restrict__ bnsc,
    float* __restrict__ out){
  const int g = blockIdx.y*512 + blockIdx.x;
  const int t = threadIdx.x, b = g >> 9;
  __shared__ float ds[32][260];
  __shared__ float hs[32][260];
  __shared__ float ps[32][68];
  __shared__ float a1s[256], d1s[256];
  __shared__ float red[256];
  for (int i = t; i < 2048; i += 256){
    int r = i >> 6, c = (i & 63) * 4;
    *(float4*)(&ds[r][c]) = *(const float4*)(g_dsa + ((size_t)g*32 + r)*256 + c);
  }
  for (int i = t; i < 512; i += 256){
    int r = i >> 4, c = (i & 15) * 4;
    int idx = g_knn_idx[g*32 + r];
    *(float4*)(&ps[r][c]) = *(const float4*)(points + ((size_t)b*NPTS + idx)*64 + c);
  }
  {
    float gg2 = bn1[t], be = bn1[256+t], m = bn1[512+t], v = bn1[768+t];
    float a = gg2 * rsqrtf(v + 1e-5f);
    a1s[t] = a; d1s[t] = b1[t]*a + (be - m*a);
  }
  __syncthreads();
  // C1: h = relu(bn1(dsa @ W1 + b1))
  {
    const int kg = t >> 6, c0 = (t & 63) * 4;
    float acc[8][4] = {};
    for (int j = 0; j < 256; j += 4){
      float wvv[4][4];
      for (int jj = 0; jj < 4; jj++){
        float4 wrow = *(const float4*)(w1 + (j+jj)*256 + c0);
        wvv[jj][0] = wrow.x; wvv[jj][1] = wrow.y; wvv[jj][2] = wrow.z; wvv[jj][3] = wrow.w;
      }
      for (int r = 0; r < 8; r++){
        const float4 d4 = *(const float4*)(&ds[kg*8+r][j]);
        const float dr[4] = {d4.x, d4.y, d4.z, d4.w};
        for (int jj = 0; jj < 4; jj++)
          for (int i = 0; i < 4; i++) acc[r][i] += dr[jj]*wvv[jj][i];
      }
    }
    for (int r = 0; r < 8; r++){
      float4 o;
      o.x = fmaxf(acc[r][0]*a1s[c0+0] + d1s[c0+0], 0.f);
      o.y = fmaxf(acc[r][1]*a1s[c0+1] + d1s[c0+1], 0.f);
      o.z = fmaxf(acc[r][2]*a1s[c0+2] + d1s[c0+2], 0.f);
      o.w = fmaxf(acc[r][3]*a1s[c0+3] + d1s[c0+3], 0.f);
      *(float4*)(&hs[kg*8+r][c0]) = o;
    }
  }
  __syncthreads();
  // C2: layer 2 + shortcut + relu + max over k
  {
    const int c = t & 127, kh = t >> 7;
    float g2 = bn2[c], be2 = bn2[128+c], m2 = bn2[256+c], v2 = bn2[384+c];
    float a2 = g2 * rsqrtf(v2 + 1e-5f);
    float d2v = b2[c]*a2 + (be2 - m2*a2);
    float gsc = bnsc[c], besc = bnsc[128+c], msc = bnsc[256+c], vsc = bnsc[384+c];
    float asc = gsc * rsqrtf(vsc + 1e-5f);
    float dscv = bsc[c]*asc + (besc - msc*asc);
    float accm[16] = {};
    for (int j = 0; j < 256; j += 4){
      float w0 = w2[j*128+c], w1v = w2[(j+1)*128+c];
      float w2v = w2[(j+2)*128+c], w3 = w2[(j+3)*128+c];
      for (int r = 0; r < 16; r++){
        const float4 h4 = *(const float4*)(&hs[kh*16+r][j]);
        accm[r] += h4.x*w0; accm[r] += h4.y*w1v; accm[r] += h4.z*w2v; accm[r] += h4.w*w3;
      }
    }
    float accs[16] = {};
    for (int j = 0; j < 64; j += 4){
      float w0 = wsc[j*128+c], w1v = wsc[(j+1)*128+c];
      float w2v = wsc[(j+2)*128+c], w3 = wsc[(j+3)*128+c];
      for (int r = 0; r < 16; r++){
        const float4 p4 = *(const float4*)(&ps[kh*16+r][j]);
        accs[r] += p4.x*w0; accs[r] += p4.y*w1v; accs[r] += p4.z*w2v; accs[r] += p4.w*w3;
      }
    }
    float mx = -1e30f;
    for (int r = 0; r < 16; r++){
      float mainv = accm[r]*a2 + d2v;
      float scv = fmaxf(accs[r]*asc + dscv, 0.f);
      mx = fmaxf(mx, fmaxf(mainv + scv, 0.f));
    }
    red[t] = mx;
  }
  __syncthreads();
  if (t < 128){
    float m = fmaxf(red[t], red[t+128]);
    out[12288 + (size_t)g*128 + t] = m;
  }
}

// ----------------------------------------------------------------
extern "C" void kernel_launch(void* const* d_in, const int* in_sizes, int n_in,
                              void* d_out, int out_size, void* d_ws, size_t ws_size,
                              hipStream_t stream){
  (void)in_sizes; (void)n_in; (void)d_ws; (void)ws_size; (void)out_size;
  const float* xyz      = (const float*)d_in[0];
  const float* points   = (const float*)d_in[1];
  const int*   fstart   = (const int*)  d_in[2];
  const float* pos_w1   = (const float*)d_in[3];
  const float* pos_b1   = (const float*)d_in[4];
  const float* pos_bn1  = (const float*)d_in[5];
  const float* pos_w2   = (const float*)d_in[6];
  const float* pos_b2   = (const float*)d_in[7];
  const float* pos_bn2  = (const float*)d_in[8];
  const float* nsa_wq   = (const float*)d_in[9];
  const float* nsa_bq   = (const float*)d_in[10];
  const float* nsa_wk   = (const float*)d_in[11];
  const float* nsa_bk   = (const float*)d_in[12];
  const float* nsa_wv   = (const float*)d_in[13];
  const float* nsa_bv   = (const float*)d_in[14];
  const float* nsa_g    = (const float*)d_in[15];
  const float* gam_g    = (const float*)d_in[16];
  const float* cat_w1   = (const float*)d_in[17];
  const float* cat_b1   = (const float*)d_in[18];
  const float* cat_bn1  = (const float*)d_in[19];
  const float* cat_w2   = (const float*)d_in[20];
  const float* cat_b2   = (const float*)d_in[21];
  const float* cat_bn2  = (const float*)d_in[22];
  const float* sc_w     = (const float*)d_in[23];
  const float* sc_b     = (const float*)d_in[24];
  const float* sc_bn    = (const float*)d_in[25];
  float* out = (float*)d_out;   // output is float32

  k_fps     <<<NB, 256, 0, stream>>>(xyz, fstart, out);
  k_knn     <<<NB*NS, 256, 0, stream>>>(xyz);
  k_posembed<<<512, 256, 0, stream>>>(xyz, pos_w1, pos_b1, pos_bn1, pos_w2, pos_b2, pos_bn2);
  k_gram    <<<dim3(36, NB), 256, 0, stream>>>(points);
  k_softmax <<<NB*NS, 256, 0, stream>>>();
  k_grp     <<<dim3(512, NB), 256, 0, stream>>>(points, gam_g);
  k_nsa     <<<dim3(512, NB), 256, 0, stream>>>(points, nsa_wq, nsa_bq, nsa_wk, nsa_bk,
                                                nsa_wv, nsa_bv, nsa_g);
  k_mlp     <<<dim3(512, NB), 256, 0, stream>>>(points, cat_w1, cat_b1, cat_bn1,
                                                cat_w2, cat_b2, cat_bn2,
                                                sc_w, sc_b, sc_bn, out);
}

// Round 9
// 1830.954 us; speedup vs baseline: 2.8462x; 2.8462x over previous
//
#include <hip/hip_runtime.h>
#include <stdint.h>
#include <float.h>

typedef unsigned int uint;

#define NB 8
#define NPTS 4096
#define NS 512
#define NKN 32

// ---- static device scratch (~177 MB, allocated at module load; fully rewritten each call)
__device__ int   g_fps_idx[NB*NS];
__device__ int   g_knn_idx[NB*NS*NKN];
__device__ float g_knn_d2 [NB*NS*NKN];
__device__ float g_posb   [(size_t)NB*NS*NKN*64];    //  33.5 MB
__device__ float g_ga     [(size_t)NB*NS*NS];        //   8.4 MB
__device__ float g_dsa    [(size_t)NB*NS*NKN*256];   // 134 MB  [group*32+k][256] = [nei|grp]

__device__ __forceinline__ unsigned long long shfl_down_u64(unsigned long long v, int off){
  int lo = __shfl_down((int)(unsigned)v, off);
  int hi = __shfl_down((int)(unsigned)(v >> 32), off);
  return ((unsigned long long)(unsigned)hi << 32) | (unsigned)lo;
}
__device__ __forceinline__ unsigned long long u64max(unsigned long long a, unsigned long long b){
  return a > b ? a : b;
}
__device__ __forceinline__ unsigned long long u64min(unsigned long long a, unsigned long long b){
  return a < b ? a : b;
}
__device__ __forceinline__ void ldf8(const float* p, float* d){
  float4 a = *(const float4*)p, b = *(const float4*)(p+4);
  d[0]=a.x; d[1]=a.y; d[2]=a.z; d[3]=a.w; d[4]=b.x; d[5]=b.y; d[6]=b.z; d[7]=b.w;
}
// robust start read: int32 (start[b]) vs int64 (start[2b]; high words zero since values<4096)
__device__ __forceinline__ int read_start(const int* __restrict__ start, int b){
  int w1 = start[1], w3 = start[3], w5 = start[5], w7 = start[7];
  bool is64 = ((w1 | w3 | w5 | w7) == 0);
  int v = is64 ? start[2*b] : start[b];
  return v & (NPTS - 1);
}

// flat column order: n = k*128 + d, d<64 -> posb, d>=64 -> points gather
__device__ __forceinline__ void load_flat8(const float* __restrict__ points,
                                           int b, int row, int n, float* d){
  const int k = n >> 7, col = n & 63;
  if (n & 64){
    const int idx = g_knn_idx[((b << 9) + row)*32 + k];
    ldf8(points + (((size_t)b << 12) + idx)*64 + col, d);
  } else {
    ldf8(g_posb + (((size_t)((b << 9) + row))*32 + k)*64 + col, d);
  }
}
__device__ __forceinline__ float4 load_flat4(const float* __restrict__ points,
                                             int b, int row, int n){
  const int k = n >> 7, d = n & 127;
  if (d & 64){
    const int idx = g_knn_idx[((b << 9) + row)*32 + k];
    return *(const float4*)(points + (((size_t)b << 12) + idx)*64 + (d & 63));
  } else {
    return *(const float4*)(g_posb + (((size_t)((b << 9) + row))*32 + k)*64 + d);
  }
}
// reorganized order for Gram only: kc in [0,2048) pos (k-major), [2048,4096) pts
__device__ __forceinline__ void load_gram8(const float* __restrict__ points,
                                           int b, int row, int kc, float* d){
  if (kc < 2048){
    ldf8(g_posb + ((size_t)((b << 9) + row))*2048 + kc, d);
  } else {
    const int kc2 = kc - 2048, kg = kc2 >> 6, col = kc2 & 63;
    const int idx = g_knn_idx[((b << 9) + row)*32 + kg];
    ldf8(points + (((size_t)b << 12) + idx)*64 + col, d);
  }
}

// ---------------------------------------------------------------- FPS (f32 packed-key selection, 256 thr)
__global__ __launch_bounds__(256) void k_fps(const float* __restrict__ xyz,
                                             const int* __restrict__ start,
                                             float* __restrict__ center_out){
#pragma clang fp contract(off)
  const int b = blockIdx.x, tid = threadIdx.x;
  const float* X = xyz + (size_t)b * NPTS * 3;
  __shared__ float sx[NPTS], sy[NPTS], sz[NPTS];
  for (int p = tid; p < NPTS; p += 256){
    sx[p] = X[3*p]; sy[p] = X[3*p+1]; sz[p] = X[3*p+2];
  }
  __shared__ int s_start0;
  if (tid == 0) s_start0 = read_start(start, b);
  __syncthreads();
  float px[16], py[16], pz[16], dist[16];
  for (int i = 0; i < 16; i++){
    int p = tid*16 + i;
    px[i] = sx[p]; py[i] = sy[p]; pz[i] = sz[p];
    dist[i] = 1e10f;
  }
  __shared__ unsigned long long s_k[2][4];
  int cur = s_start0;
  for (int t = 0; t < NS; t++){
    if (tid == 0){
      g_fps_idx[b*NS + t] = cur;
      center_out[(size_t)(b*NS + t)*3 + 0] = sx[cur];
      center_out[(size_t)(b*NS + t)*3 + 1] = sy[cur];
      center_out[(size_t)(b*NS + t)*3 + 2] = sz[cur];
    }
    const float cx = sx[cur], cy = sy[cur], cz = sz[cur];
    unsigned long long k_[16];
#pragma unroll
    for (int i = 0; i < 16; i++){
      float dx = px[i]-cx, dy = py[i]-cy, dz = pz[i]-cz;
      float d = ((dx*dx) + (dy*dy)) + (dz*dz);
      dist[i] = fminf(dist[i], d);
      k_[i] = ((unsigned long long)__float_as_uint(dist[i]) << 32)
            | (unsigned)(NPTS-1 - (tid*16 + i));
    }
#pragma unroll
    for (int st = 8; st; st >>= 1)
      for (int i = 0; i < st; i++) k_[i] = u64max(k_[i], k_[i+st]);
    unsigned long long bk = k_[0];
    { unsigned long long a = shfl_down_u64(bk,16), c = shfl_down_u64(bk,32), d = shfl_down_u64(bk,48);
      bk = u64max(u64max(bk,a), u64max(c,d)); }
    { unsigned long long a = shfl_down_u64(bk,4),  c = shfl_down_u64(bk,8),  d = shfl_down_u64(bk,12);
      bk = u64max(u64max(bk,a), u64max(c,d)); }
    { unsigned long long a = shfl_down_u64(bk,1),  c = shfl_down_u64(bk,2),  d = shfl_down_u64(bk,3);
      bk = u64max(u64max(bk,a), u64max(c,d)); }
    const int par = t & 1;
    if ((tid & 63) == 0) s_k[par][tid>>6] = bk;
    __syncthreads();
    unsigned long long m = u64max(u64max(s_k[par][0], s_k[par][1]),
                                  u64max(s_k[par][2], s_k[par][3]));
    cur = NPTS-1 - (int)(unsigned)m;
  }
}

// ---------------------------------------------------------------- KNN top-32 (f32 packed-key, 1 barrier/sel)
__global__ __launch_bounds__(256) void k_knn(const float* __restrict__ xyz){
#pragma clang fp contract(off)
  const int g = blockIdx.x;            // b*512 + s
  const int b = g >> 9;
  const int tid = threadIdx.x;
  const float* X = xyz + (size_t)b * NPTS * 3;
  const int cidx = g_fps_idx[g];
  const float cx = X[3*cidx], cy = X[3*cidx+1], cz = X[3*cidx+2];
  const float cs = ((cx*cx) + (cy*cy)) + (cz*cz);
  unsigned long long kl[16];
#pragma unroll
  for (int i = 0; i < 16; i++){
    int p = tid*16 + i;
    float x = X[3*p], y = X[3*p+1], z = X[3*p+2];
    float xs2 = ((x*x) + (y*y)) + (z*z);
    float dt  = ((cx*x) + (cy*y)) + (cz*z);
    float d   = (cs + xs2) - 2.0f*dt;
    unsigned bits = __float_as_uint(d);
    unsigned mono = (bits & 0x80000000u) ? ~bits : (bits ^ 0x80000000u);
    kl[i] = ((unsigned long long)mono << 32) | (unsigned)p;
  }
  __shared__ unsigned long long s_w[2][4];
  unsigned long long last = 0;
  for (int sel = 0; sel < NKN; sel++){
    unsigned long long mk[16];
#pragma unroll
    for (int i = 0; i < 16; i++)
      mk[i] = (kl[i] > last) ? kl[i] : 0xFFFFFFFFFFFFFFFFULL;
#pragma unroll
    for (int st = 8; st; st >>= 1)
      for (int i = 0; i < st; i++) mk[i] = u64min(mk[i], mk[i+st]);
    unsigned long long bk = mk[0];
    { unsigned long long a = shfl_down_u64(bk,16), c = shfl_down_u64(bk,32), d = shfl_down_u64(bk,48);
      bk = u64min(u64min(bk,a), u64min(c,d)); }
    { unsigned long long a = shfl_down_u64(bk,4),  c = shfl_down_u64(bk,8),  d = shfl_down_u64(bk,12);
      bk = u64min(u64min(bk,a), u64min(c,d)); }
    { unsigned long long a = shfl_down_u64(bk,1),  c = shfl_down_u64(bk,2),  d = shfl_down_u64(bk,3);
      bk = u64min(u64min(bk,a), u64min(c,d)); }
    const int par = sel & 1;
    if ((tid & 63) == 0) s_w[par][tid>>6] = bk;
    __syncthreads();
    unsigned long long m = u64min(u64min(s_w[par][0], s_w[par][1]),
                                  u64min(s_w[par][2], s_w[par][3]));
    last = m;
    if (tid == 0){
      unsigned hm = (unsigned)(m >> 32);
      unsigned bits = (hm & 0x80000000u) ? (hm ^ 0x80000000u) : ~hm;
      g_knn_idx[g*NKN + sel] = (int)(unsigned)m;
      g_knn_d2 [g*NKN + sel] = __uint_as_float(bits);
    }
  }
}

// ---------------------------------------------------------------- pos-embed MLP -> g_posb (f32)
__global__ __launch_bounds__(256) void k_posembed(
    const float* __restrict__ xyz,
    const float* __restrict__ w1, const float* __restrict__ b1, const float* __restrict__ bn1,
    const float* __restrict__ w2, const float* __restrict__ b2, const float* __restrict__ bn2){
  __shared__ float w1s[320], a1s[32], d1s[32], w2s[2048], a2s[64], d2s[64];
  const int t = threadIdx.x;
  for (int i = t; i < 320; i += 256) w1s[i] = w1[i];
  for (int i = t; i < 2048; i += 256) w2s[i] = w2[i];
  if (t < 32){
    float g = bn1[t], be = bn1[32+t], m = bn1[64+t], v = bn1[96+t];
    float a = g * rsqrtf(v + 1e-5f);
    a1s[t] = a; d1s[t] = b1[t]*a + (be - m*a);
  }
  if (t < 64){
    float g = bn2[t], be = bn2[64+t], m = bn2[128+t], v = bn2[192+t];
    float a = g * rsqrtf(v + 1e-5f);
    a2s[t] = a; d2s[t] = b2[t]*a + (be - m*a);
  }
  __syncthreads();
  const int row = blockIdx.x*256 + t;          // (b*512+s)*32 + k
  const int b = row >> 14;
  const int g = row >> 5;
  const float* X = xyz + (size_t)b * NPTS * 3;
  const int ci = g_fps_idx[g];
  const int ni = g_knn_idx[row];
  float c0 = X[3*ci], c1 = X[3*ci+1], c2 = X[3*ci+2];
  float n0 = X[3*ni], n1 = X[3*ni+1], n2 = X[3*ni+2];
  float feat[10] = {c0,c1,c2, n0,n1,n2, n0-c0,n1-c1,n2-c2, g_knn_d2[row]};
  float h[32];
  for (int o = 0; o < 32; o++){
    float acc = 0.f;
    for (int j = 0; j < 10; j++) acc += feat[j]*w1s[j*32+o];
    h[o] = fmaxf(acc*a1s[o] + d1s[o], 0.f);
  }
  float* xr = g_posb + (size_t)row * 64;
  for (int o = 0; o < 64; o++){
    float acc = 0.f;
    for (int j = 0; j < 32; j++) acc += h[j]*w2s[j*64+o];
    xr[o] = fmaxf(acc*a2s[o] + d2s[o], 0.f);
  }
}

// ---------------------------------------------------------------- Gram = flat @ flat^T (f32, symmetric)
__global__ __launch_bounds__(256) void k_gram(const float* __restrict__ points){
  const int b = blockIdx.y;
  int ti = 0, rem = blockIdx.x;
  while (rem >= 8 - ti){ rem -= 8 - ti; ti++; }
  const int tj = ti + rem;
  const int i0 = ti * 64, j0 = tj * 64;
  __shared__ float As[32][68];
  __shared__ float Bs[32][68];
  const int t = threadIdx.x, tx = t & 15, ty = t >> 4;
  float acc[4][4] = {};
  for (int k0 = 0; k0 < 4096; k0 += 32){
    {
      int r = t >> 2, kk = (t & 3) * 8;
      float ta[8], tb[8];
      load_gram8(points, b, i0+r, k0+kk, ta);
      load_gram8(points, b, j0+r, k0+kk, tb);
      for (int jj = 0; jj < 8; jj++){
        int k = kk + jj;
        int c = (r + (k & 24)) & 63;   // rotated column, conflict-free store
        As[k][c] = ta[jj]; Bs[k][c] = tb[jj];
      }
    }
    __syncthreads();
    for (int kk = 0; kk < 32; kk++){
      const int rot = kk & 24;
      const float4 a4 = *(const float4*)(&As[kk][(ty*4 + rot) & 63]);
      const float4 b4 = *(const float4*)(&Bs[kk][(tx*4 + rot) & 63]);
      const float ar[4] = {a4.x,a4.y,a4.z,a4.w};
      const float br[4] = {b4.x,b4.y,b4.z,b4.w};
      for (int ia = 0; ia < 4; ia++)
        for (int ib = 0; ib < 4; ib++) acc[ia][ib] += ar[ia]*br[ib];
    }
    __syncthreads();
  }
  float* C = g_ga + (size_t)b * NS * NS;
  for (int ia = 0; ia < 4; ia++){
    float4 o = {acc[ia][0], acc[ia][1], acc[ia][2], acc[ia][3]};
    *(float4*)(C + (size_t)(i0+ty*4+ia)*NS + j0 + tx*4) = o;
  }
  if (ti != tj){
    for (int ib = 0; ib < 4; ib++){
      float4 o = {acc[0][ib], acc[1][ib], acc[2][ib], acc[3][ib]};
      *(float4*)(C + (size_t)(j0+tx*4+ib)*NS + i0 + ty*4) = o;
    }
  }
}

// ---------------------------------------------------------------- row softmax (in place)
__global__ __launch_bounds__(256) void k_softmax(){
  float* R = g_ga + (size_t)blockIdx.x * NS;
  const int t = threadIdx.x;
  float v0 = R[t], v1 = R[t+256];
  __shared__ float sm[4], ssum[4];
  float m = fmaxf(v0, v1);
  for (int off = 32; off; off >>= 1) m = fmaxf(m, __shfl_down(m, off));
  if ((t & 63) == 0) sm[t>>6] = m;
  __syncthreads();
  float mm = fmaxf(fmaxf(sm[0], sm[1]), fmaxf(sm[2], sm[3]));
  float e0 = expf(v0 - mm), e1 = expf(v1 - mm);
  float s = e0 + e1;
  for (int off = 32; off; off >>= 1) s += __shfl_down(s, off);
  if ((t & 63) == 0) ssum[t>>6] = s;
  __syncthreads();
  float inv = 1.0f / (ssum[0]+ssum[1]+ssum[2]+ssum[3]);
  R[t] = e0*inv; R[t+256] = e1*inv;
}

// ---------------------------------------------------------------- grp: ga @ flat, fused gamma*+x -> g_dsa[...,128:256]
__global__ __launch_bounds__(256) void k_grp(const float* __restrict__ points,
                                             const float* __restrict__ gam_g){
  const int b = blockIdx.y;
  const int s0 = (blockIdx.x >> 6) * 64, n0 = (blockIdx.x & 63) * 64;
  const float* G = g_ga + (size_t)b * NS * NS;
  __shared__ float As[32][68];
  __shared__ float Bs[32][68];
  const int t = threadIdx.x, tx = t & 15, ty = t >> 4;
  float acc[4][4] = {};
  for (int k0 = 0; k0 < NS; k0 += 32){
    {
      int r = t >> 2, kk = (t & 3) * 8;
      const float* pa = G + (size_t)(s0+r)*NS + k0 + kk;
      float4 v0 = *(const float4*)pa, v1 = *(const float4*)(pa+4);
      const float va[8] = {v0.x,v0.y,v0.z,v0.w,v1.x,v1.y,v1.z,v1.w};
      for (int jj = 0; jj < 8; jj++){
        int k = kk + jj;
        As[k][(r + (k & 24)) & 63] = va[jj];   // rotated column, conflict-free store
      }
      int k2 = t >> 3, c = (t & 7) * 8;
      float tb[8];
      load_flat8(points, b, k0+k2, n0+c, tb);
      float4 w0 = {tb[0],tb[1],tb[2],tb[3]}, w1 = {tb[4],tb[5],tb[6],tb[7]};
      *(float4*)(&Bs[k2][c])   = w0;
      *(float4*)(&Bs[k2][c+4]) = w1;
    }
    __syncthreads();
    for (int kk = 0; kk < 32; kk++){
      const float4 a4 = *(const float4*)(&As[kk][(ty*4 + (kk & 24)) & 63]);
      const float4 b4 = *(const float4*)(&Bs[kk][tx*4]);
      const float ar[4] = {a4.x,a4.y,a4.z,a4.w};
      const float br[4] = {b4.x,b4.y,b4.z,b4.w};
      for (int ia = 0; ia < 4; ia++)
        for (int ib = 0; ib < 4; ib++) acc[ia][ib] += ar[ia]*br[ib];
    }
    __syncthreads();
  }
  const float gmg = gam_g[0];
  const int n = n0 + tx*4;
  const int kq = n >> 7, dq = n & 127;
  for (int ia = 0; ia < 4; ia++){
    int s = s0 + ty*4 + ia;
    float4 xv = load_flat4(points, b, s, n);
    float4 o = {gmg*acc[ia][0]+xv.x, gmg*acc[ia][1]+xv.y,
                gmg*acc[ia][2]+xv.z, gmg*acc[ia][3]+xv.w};
    *(float4*)(g_dsa + ((size_t)((b*NS + s)*32 + kq))*256 + 128 + dq) = o;
  }
}

// ---------------------------------------------------------------- NSA: Q/K/V + softmax + PV -> g_dsa[...,0:128]
// Weight LDS staging retained from round 8 (kills the 32x per-block weight
// re-streaming through L2), but with loop-unroll pinning to prevent the round-8
// register-spill catastrophe (VGPR 256, 4.8GB scratch writes): Q/K j-loop unroll 8,
// wv tile loop unroll 1, inner jl loop unroll 4. j ascends 0..127 across tiles
// -> bit-exact vs the unstaged version.
__global__ __launch_bounds__(256) void k_nsa(const float* __restrict__ points,
    const float* __restrict__ wq, const float* __restrict__ bq,
    const float* __restrict__ wk, const float* __restrict__ bk,
    const float* __restrict__ wv, const float* __restrict__ bv_,
    const float* __restrict__ nsa_g){
  const int g = blockIdx.y*512 + blockIdx.x;
  const int t = threadIdx.x, b = g >> 9;
  const int r = t >> 3, c = t & 7;
  __shared__ float xs[32][132];
  __shared__ float vs[32][132];          // float4 view: row stride 33
  __shared__ float qs[32][17], ks[32][17];
  __shared__ float at[32][33];
  __shared__ float wqs[2048];            // 128x16
  __shared__ float wks[2048];            // 128x16
  __shared__ float wvs[4096];            // 32x128 tile (reused 4x)
  // stage x row r (8 lanes of subgroup r cover the row) + wq/wk
  {
    float tmp[8];
    ldf8(g_posb + ((size_t)g*32 + r)*64 + c*8, tmp);
    for (int j = 0; j < 8; j++) xs[r][c*8+j] = tmp[j];
    int idx = g_knn_idx[g*32 + r];
    ldf8(points + ((size_t)b*NPTS + idx)*64 + c*8, tmp);
    for (int j = 0; j < 8; j++) xs[r][64+c*8+j] = tmp[j];
  }
  for (int i = t; i < 512; i += 256){
    ((float4*)wqs)[i] = ((const float4*)wq)[i];
    ((float4*)wks)[i] = ((const float4*)wk)[i];
  }
  __syncthreads();
  // Q/K projections from LDS (thread computes q[r][c], q[r][c+8], k[r][c], k[r][c+8])
  {
    float aq0 = bq[c], aq1 = bq[c+8], ak0 = bk[c], ak1 = bk[c+8];
#pragma unroll 8
    for (int j = 0; j < 128; j++){
      float xv = xs[r][j];
      aq0 += xv * wqs[j*16+c];
      aq1 += xv * wqs[j*16+c+8];
      ak0 += xv * wks[j*16+c];
      ak1 += xv * wks[j*16+c+8];
    }
    qs[r][c] = aq0; qs[r][c+8] = aq1; ks[r][c] = ak0; ks[r][c+8] = ak1;
  }
  // V projection, channels d = 32w + 4c + ii; wv streamed through LDS in 32-row tiles
  {
    const float4* bv4 = (const float4*)bv_;
    float4 va = bv4[c], vb = bv4[8+c], vc4 = bv4[16+c], vd = bv4[24+c];
#pragma unroll 1
    for (int t4 = 0; t4 < 4; t4++){
      if (t4) __syncthreads();           // prior tile's reads complete before overwrite
      for (int i = t; i < 1024; i += 256)
        ((float4*)wvs)[i] = ((const float4*)wv)[(size_t)t4*1024 + i];
      __syncthreads();
#pragma unroll 4
      for (int jl = 0; jl < 32; jl++){
        float xv = xs[r][t4*32 + jl];
        const float4* row = (const float4*)(wvs + jl*128);
        float4 w0 = row[c], w1 = row[8+c], w2 = row[16+c], w3 = row[24+c];
        va.x += xv*w0.x;  va.y += xv*w0.y;  va.z += xv*w0.z;  va.w += xv*w0.w;
        vb.x += xv*w1.x;  vb.y += xv*w1.y;  vb.z += xv*w1.z;  vb.w += xv*w1.w;
        vc4.x += xv*w2.x; vc4.y += xv*w2.y; vc4.z += xv*w2.z; vc4.w += xv*w2.w;
        vd.x += xv*w3.x;  vd.y += xv*w3.y;  vd.z += xv*w3.z;  vd.w += xv*w3.w;
      }
    }
    float4* vrow = (float4*)(&vs[r][0]);
    vrow[c] = va; vrow[8+c] = vb; vrow[16+c] = vc4; vrow[24+c] = vd;
  }
  __syncthreads();   // ks / vs cross-wave visibility
  // QK^T: s[jj] = q[r] . k[4c+jj]
  float p0, p1, p2, p3;
  {
    float s[4];
    for (int jj = 0; jj < 4; jj++){
      int j = 4*c + jj; float acc = 0.f;
      for (int cc = 0; cc < 16; cc++) acc += qs[r][cc] * ks[j][cc];
      s[jj] = acc;
    }
    // row softmax across the 8-lane subgroup (all lanes active)
    float m = fmaxf(fmaxf(s[0], s[1]), fmaxf(s[2], s[3]));
    m = fmaxf(m, __shfl_xor(m, 1));
    m = fmaxf(m, __shfl_xor(m, 2));
    m = fmaxf(m, __shfl_xor(m, 4));
    float e0 = expf(s[0]-m), e1 = expf(s[1]-m), e2 = expf(s[2]-m), e3 = expf(s[3]-m);
    float sum = ((e0 + e1) + (e2 + e3));
    sum += __shfl_xor(sum, 1);
    sum += __shfl_xor(sum, 2);
    sum += __shfl_xor(sum, 4);
    float inv = 1.0f / sum;
    p0 = e0*inv; p1 = e1*inv; p2 = e2*inv; p3 = e3*inv;
    at[r][4*c+0] = p0; at[r][4*c+1] = p1; at[r][4*c+2] = p2; at[r][4*c+3] = p3;
  }
  // PV + gamma*.+x residual (at row r is wave-local; vs synced above)
  {
    float4 a0 = {0,0,0,0}, a1 = {0,0,0,0}, a2 = {0,0,0,0}, a3 = {0,0,0,0};
    for (int j = 0; j < 32; j++){
      float a = at[r][j];
      const float4* vrow = (const float4*)(&vs[j][0]);
      float4 w0 = vrow[c], w1 = vrow[8+c], w2 = vrow[16+c], w3 = vrow[24+c];
      a0.x += a*w0.x; a0.y += a*w0.y; a0.z += a*w0.z; a0.w += a*w0.w;
      a1.x += a*w1.x; a1.y += a*w1.y; a1.z += a*w1.z; a1.w += a*w1.w;
      a2.x += a*w2.x; a2.y += a*w2.y; a2.z += a*w2.z; a2.w += a*w2.w;
      a3.x += a*w3.x; a3.y += a*w3.y; a3.z += a*w3.z; a3.w += a*w3.w;
    }
    const float gmn = nsa_g[0];
    float* dst = g_dsa + ((size_t)g*32 + r)*256;
    float4 x0 = *(const float4*)(&xs[r][ 0+4*c]);
    float4 x1 = *(const float4*)(&xs[r][32+4*c]);
    float4 x2 = *(const float4*)(&xs[r][64+4*c]);
    float4 x3 = *(const float4*)(&xs[r][96+4*c]);
    float4 o0 = {gmn*a0.x+x0.x, gmn*a0.y+x0.y, gmn*a0.z+x0.z, gmn*a0.w+x0.w};
    float4 o1 = {gmn*a1.x+x1.x, gmn*a1.y+x1.y, gmn*a1.z+x1.z, gmn*a1.w+x1.w};
    float4 o2 = {gmn*a2.x+x2.x, gmn*a2.y+x2.y, gmn*a2.z+x2.z, gmn*a2.w+x2.w};
    float4 o3 = {gmn*a3.x+x3.x, gmn*a3.y+x3.y, gmn*a3.z+x3.z, gmn*a3.w+x3.w};
    *(float4*)(dst +  0 + 4*c) = o0;
    *(float4*)(dst + 32 + 4*c) = o1;
    *(float4*)(dst + 64 + 4*c) = o2;
    *(float4*)(dst + 96 + 4*c) = o3;
  }
}

// ---------------------------------------------------------------- cat MLP + shortcut + maxpool -> out
// Round-3 structure (measured best: 530us). 256 threads, separate hs buffer.
__global__ __launch_bounds__(256) void k_mlp(const float* __restrict__ points,
    const float* __restrict__ w1, const float* __restrict__ b1, const float* __restrict__ bn1,
    const float* __restrict__ w2, const float* __restrict__ b2, const float* __restrict__ bn2,
    const float* __restrict__ wsc, const float* __restrict__ bsc, const float* __restrict__ bnsc,
    float* __restrict__ out){
  const int g = blockIdx.y*512 + blockIdx.x;
  const int t = threadIdx.x, b = g >> 9;
  __shared__ float ds[32][260];
  __shared__ float hs[32][260];
  __shared__ float ps[32][68];
  __shared__ float a1s[256], d1s[256];
  __shared__ float red[256];
  for (int i = t; i < 2048; i += 256){
    int r = i >> 6, c = (i & 63) * 4;
    *(float4*)(&ds[r][c]) = *(const float4*)(g_dsa + ((size_t)g*32 + r)*256 + c);
  }
  for (int i = t; i < 512; i += 256){
    int r = i >> 4, c = (i & 15) * 4;
    int idx = g_knn_idx[g*32 + r];
    *(float4*)(&ps[r][c]) = *(const float4*)(points + ((size_t)b*NPTS + idx)*64 + c);
  }
  {
    float gg2 = bn1[t], be = bn1[256+t], m = bn1[512+t], v = bn1[768+t];
    float a = gg2 * rsqrtf(v + 1e-5f);
    a1s[t] = a; d1s[t] = b1[t]*a + (be - m*a);
  }
  __syncthreads();
  // C1: h = relu(bn1(dsa @ W1 + b1))
  {
    const int kg = t >> 6, c0 = (t & 63) * 4;
    float acc[8][4] = {};
    for (int j = 0; j < 256; j += 4){
      float wvv[4][4];
      for (int jj = 0; jj < 4; jj++){
        float4 wrow = *(const float4*)(w1 + (j+jj)*256 + c0);
        wvv[jj][0] = wrow.x; wvv[jj][1] = wrow.y; wvv[jj][2] = wrow.z; wvv[jj][3] = wrow.w;
      }
      for (int r = 0; r < 8; r++){
        const float4 d4 = *(const float4*)(&ds[kg*8+r][j]);
        const float dr[4] = {d4.x, d4.y, d4.z, d4.w};
        for (int jj = 0; jj < 4; jj++)
          for (int i = 0; i < 4; i++) acc[r][i] += dr[jj]*wvv[jj][i];
      }
    }
    for (int r = 0; r < 8; r++){
      float4 o;
      o.x = fmaxf(acc[r][0]*a1s[c0+0] + d1s[c0+0], 0.f);
      o.y = fmaxf(acc[r][1]*a1s[c0+1] + d1s[c0+1], 0.f);
      o.z = fmaxf(acc[r][2]*a1s[c0+2] + d1s[c0+2], 0.f);
      o.w = fmaxf(acc[r][3]*a1s[c0+3] + d1s[c0+3], 0.f);
      *(float4*)(&hs[kg*8+r][c0]) = o;
    }
  }
  __syncthreads();
  // C2: layer 2 + shortcut + relu + max over k
  {
    const int c = t & 127, kh = t >> 7;
    float g2 = bn2[c], be2 = bn2[128+c], m2 = bn2[256+c], v2 = bn2[384+c];
    float a2 = g2 * rsqrtf(v2 + 1e-5f);
    float d2v = b2[c]*a2 + (be2 - m2*a2);
    float gsc = bnsc[c], besc = bnsc[128+c], msc = bnsc[256+c], vsc = bnsc[384+c];
    float asc = gsc * rsqrtf(vsc + 1e-5f);
    float dscv = bsc[c]*asc + (besc - msc*asc);
    float accm[16] = {};
    for (int j = 0; j < 256; j += 4){
      float w0 = w2[j*128+c], w1v = w2[(j+1)*128+c];
      float w2v = w2[(j+2)*128+c], w3 = w2[(j+3)*128+c];
      for (int r = 0; r < 16; r++){
        const float4 h4 = *(const float4*)(&hs[kh*16+r][j]);
        accm[r] += h4.x*w0; accm[r] += h4.y*w1v; accm[r] += h4.z*w2v; accm[r] += h4.w*w3;
      }
    }
    float accs[16] = {};
    for (int j = 0; j < 64; j += 4){
      float w0 = wsc[j*128+c], w1v = wsc[(j+1)*128+c];
      float w2v = wsc[(j+2)*128+c], w3 = wsc[(j+3)*128+c];
      for (int r = 0; r < 16; r++){
        const float4 p4 = *(const float4*)(&ps[kh*16+r][j]);
        accs[r] += p4.x*w0; accs[r] += p4.y*w1v; accs[r] += p4.z*w2v; accs[r] += p4.w*w3;
      }
    }
    float mx = -1e30f;
    for (int r = 0; r < 16; r++){
      float mainv = accm[r]*a2 + d2v;
      float scv = fmaxf(accs[r]*asc + dscv, 0.f);
      mx = fmaxf(mx, fmaxf(mainv + scv, 0.f));
    }
    red[t] = mx;
  }
  __syncthreads();
  if (t < 128){
    float m = fmaxf(red[t], red[t+128]);
    out[12288 + (size_t)g*128 + t] = m;
  }
}

// ----------------------------------------------------------------
extern "C" void kernel_launch(void* const* d_in, const int* in_sizes, int n_in,
                              void* d_out, int out_size, void* d_ws, size_t ws_size,
                              hipStream_t stream){
  (void)in_sizes; (void)n_in; (void)d_ws; (void)ws_size; (void)out_size;
  const float* xyz      = (const float*)d_in[0];
  const float* points   = (const float*)d_in[1];
  const int*   fstart   = (const int*)  d_in[2];
  const float* pos_w1   = (const float*)d_in[3];
  const float* pos_b1   = (const float*)d_in[4];
  const float* pos_bn1  = (const float*)d_in[5];
  const float* pos_w2   = (const float*)d_in[6];
  const float* pos_b2   = (const float*)d_in[7];
  const float* pos_bn2  = (const float*)d_in[8];
  const float* nsa_wq   = (const float*)d_in[9];
  const float* nsa_bq   = (const float*)d_in[10];
  const float* nsa_wk   = (const float*)d_in[11];
  const float* nsa_bk   = (const float*)d_in[12];
  const float* nsa_wv   = (const float*)d_in[13];
  const float* nsa_bv   = (const float*)d_in[14];
  const float* nsa_g    = (const float*)d_in[15];
  const float* gam_g    = (const float*)d_in[16];
  const float* cat_w1   = (const float*)d_in[17];
  const float* cat_b1   = (const float*)d_in[18];
  const float* cat_bn1  = (const float*)d_in[19];
  const float* cat_w2   = (const float*)d_in[20];
  const float* cat_b2   = (const float*)d_in[21];
  const float* cat_bn2  = (const float*)d_in[22];
  const float* sc_w     = (const float*)d_in[23];
  const float* sc_b     = (const float*)d_in[24];
  const float* sc_bn    = (const float*)d_in[25];
  float* out = (float*)d_out;   // output is float32

  k_fps     <<<NB, 256, 0, stream>>>(xyz, fstart, out);
  k_knn     <<<NB*NS, 256, 0, stream>>>(xyz);
  k_posembed<<<512, 256, 0, stream>>>(xyz, pos_w1, pos_b1, pos_bn1, pos_w2, pos_b2, pos_bn2);
  k_gram    <<<dim3(36, NB), 256, 0, stream>>>(points);
  k_softmax <<<NB*NS, 256, 0, stream>>>();
  k_grp     <<<dim3(512, NB), 256, 0, stream>>>(points, gam_g);
  k_nsa     <<<dim3(512, NB), 256, 0, stream>>>(points, nsa_wq, nsa_bq, nsa_wk, nsa_bk,
                                                nsa_wv, nsa_bv, nsa_g);
  k_mlp     <<<dim3(512, NB), 256, 0, stream>>>(points, cat_w1, cat_b1, cat_bn1,
                                                cat_w2, cat_b2, cat_bn2,
                                                sc_w, sc_b, sc_bn, out);
}

// Round 10
// 1739.107 us; speedup vs baseline: 2.9965x; 1.0528x over previous
//
#include <hip/hip_runtime.h>
#include <stdint.h>
#include <float.h>

typedef unsigned int uint;

#define NB 8
#define NPTS 4096
#define NS 512
#define NKN 32

// ---- static device scratch (~210 MB, allocated at module load; fully rewritten each call)
__device__ int   g_fps_idx[NB*NS];
__device__ int   g_knn_idx[NB*NS*NKN];
__device__ float g_knn_d2 [NB*NS*NKN];
__device__ float g_posb   [(size_t)NB*NS*NKN*64];    //  33.5 MB
__device__ float g_ga     [(size_t)NB*NS*NS];        //   8.4 MB
__device__ float g_gp     [(size_t)4*NB*NS*NS];      //  33.5 MB gram K-chunk partials
__device__ float g_dsa    [(size_t)NB*NS*NKN*256];   // 134 MB  [group*32+k][256] = [nei|grp]

__device__ __forceinline__ unsigned long long shfl_down_u64(unsigned long long v, int off){
  int lo = __shfl_down((int)(unsigned)v, off);
  int hi = __shfl_down((int)(unsigned)(v >> 32), off);
  return ((unsigned long long)(unsigned)hi << 32) | (unsigned)lo;
}
__device__ __forceinline__ unsigned long long u64max(unsigned long long a, unsigned long long b){
  return a > b ? a : b;
}
__device__ __forceinline__ unsigned long long u64min(unsigned long long a, unsigned long long b){
  return a < b ? a : b;
}
__device__ __forceinline__ void ldf8(const float* p, float* d){
  float4 a = *(const float4*)p, b = *(const float4*)(p+4);
  d[0]=a.x; d[1]=a.y; d[2]=a.z; d[3]=a.w; d[4]=b.x; d[5]=b.y; d[6]=b.z; d[7]=b.w;
}
// robust start read: int32 (start[b]) vs int64 (start[2b]; high words zero since values<4096)
__device__ __forceinline__ int read_start(const int* __restrict__ start, int b){
  int w1 = start[1], w3 = start[3], w5 = start[5], w7 = start[7];
  bool is64 = ((w1 | w3 | w5 | w7) == 0);
  int v = is64 ? start[2*b] : start[b];
  return v & (NPTS - 1);
}

// flat column order: n = k*128 + d, d<64 -> posb, d>=64 -> points gather
__device__ __forceinline__ void load_flat8(const float* __restrict__ points,
                                           int b, int row, int n, float* d){
  const int k = n >> 7, col = n & 63;
  if (n & 64){
    const int idx = g_knn_idx[((b << 9) + row)*32 + k];
    ldf8(points + (((size_t)b << 12) + idx)*64 + col, d);
  } else {
    ldf8(g_posb + (((size_t)((b << 9) + row))*32 + k)*64 + col, d);
  }
}
__device__ __forceinline__ float4 load_flat4(const float* __restrict__ points,
                                             int b, int row, int n){
  const int k = n >> 7, d = n & 127;
  if (d & 64){
    const int idx = g_knn_idx[((b << 9) + row)*32 + k];
    return *(const float4*)(points + (((size_t)b << 12) + idx)*64 + (d & 63));
  } else {
    return *(const float4*)(g_posb + (((size_t)((b << 9) + row))*32 + k)*64 + d);
  }
}
// reorganized order for Gram only: kc in [0,2048) pos (k-major), [2048,4096) pts
__device__ __forceinline__ void load_gram8(const float* __restrict__ points,
                                           int b, int row, int kc, float* d){
  if (kc < 2048){
    ldf8(g_posb + ((size_t)((b << 9) + row))*2048 + kc, d);
  } else {
    const int kc2 = kc - 2048, kg = kc2 >> 6, col = kc2 & 63;
    const int idx = g_knn_idx[((b << 9) + row)*32 + kg];
    ldf8(points + (((size_t)b << 12) + idx)*64 + col, d);
  }
}

// ---------------------------------------------------------------- FPS (f32 packed-key selection, 256 thr)
__global__ __launch_bounds__(256) void k_fps(const float* __restrict__ xyz,
                                             const int* __restrict__ start,
                                             float* __restrict__ center_out){
#pragma clang fp contract(off)
  const int b = blockIdx.x, tid = threadIdx.x;
  const float* X = xyz + (size_t)b * NPTS * 3;
  __shared__ float sx[NPTS], sy[NPTS], sz[NPTS];
  for (int p = tid; p < NPTS; p += 256){
    sx[p] = X[3*p]; sy[p] = X[3*p+1]; sz[p] = X[3*p+2];
  }
  __shared__ int s_start0;
  if (tid == 0) s_start0 = read_start(start, b);
  __syncthreads();
  float px[16], py[16], pz[16], dist[16];
  for (int i = 0; i < 16; i++){
    int p = tid*16 + i;
    px[i] = sx[p]; py[i] = sy[p]; pz[i] = sz[p];
    dist[i] = 1e10f;
  }
  __shared__ unsigned long long s_k[2][4];
  int cur = s_start0;
  for (int t = 0; t < NS; t++){
    if (tid == 0){
      g_fps_idx[b*NS + t] = cur;
      center_out[(size_t)(b*NS + t)*3 + 0] = sx[cur];
      center_out[(size_t)(b*NS + t)*3 + 1] = sy[cur];
      center_out[(size_t)(b*NS + t)*3 + 2] = sz[cur];
    }
    const float cx = sx[cur], cy = sy[cur], cz = sz[cur];
    unsigned long long k_[16];
#pragma unroll
    for (int i = 0; i < 16; i++){
      float dx = px[i]-cx, dy = py[i]-cy, dz = pz[i]-cz;
      float d = ((dx*dx) + (dy*dy)) + (dz*dz);
      dist[i] = fminf(dist[i], d);
      k_[i] = ((unsigned long long)__float_as_uint(dist[i]) << 32)
            | (unsigned)(NPTS-1 - (tid*16 + i));
    }
#pragma unroll
    for (int st = 8; st; st >>= 1)
      for (int i = 0; i < st; i++) k_[i] = u64max(k_[i], k_[i+st]);
    unsigned long long bk = k_[0];
    { unsigned long long a = shfl_down_u64(bk,16), c = shfl_down_u64(bk,32), d = shfl_down_u64(bk,48);
      bk = u64max(u64max(bk,a), u64max(c,d)); }
    { unsigned long long a = shfl_down_u64(bk,4),  c = shfl_down_u64(bk,8),  d = shfl_down_u64(bk,12);
      bk = u64max(u64max(bk,a), u64max(c,d)); }
    { unsigned long long a = shfl_down_u64(bk,1),  c = shfl_down_u64(bk,2),  d = shfl_down_u64(bk,3);
      bk = u64max(u64max(bk,a), u64max(c,d)); }
    const int par = t & 1;
    if ((tid & 63) == 0) s_k[par][tid>>6] = bk;
    __syncthreads();
    unsigned long long m = u64max(u64max(s_k[par][0], s_k[par][1]),
                                  u64max(s_k[par][2], s_k[par][3]));
    cur = NPTS-1 - (int)(unsigned)m;
  }
}

// ---------------------------------------------------------------- KNN top-32 (f32 packed-key, 1 barrier/sel)
__global__ __launch_bounds__(256) void k_knn(const float* __restrict__ xyz){
#pragma clang fp contract(off)
  const int g = blockIdx.x;            // b*512 + s
  const int b = g >> 9;
  const int tid = threadIdx.x;
  const float* X = xyz + (size_t)b * NPTS * 3;
  const int cidx = g_fps_idx[g];
  const float cx = X[3*cidx], cy = X[3*cidx+1], cz = X[3*cidx+2];
  const float cs = ((cx*cx) + (cy*cy)) + (cz*cz);
  unsigned long long kl[16];
#pragma unroll
  for (int i = 0; i < 16; i++){
    int p = tid*16 + i;
    float x = X[3*p], y = X[3*p+1], z = X[3*p+2];
    float xs2 = ((x*x) + (y*y)) + (z*z);
    float dt  = ((cx*x) + (cy*y)) + (cz*z);
    float d   = (cs + xs2) - 2.0f*dt;
    unsigned bits = __float_as_uint(d);
    unsigned mono = (bits & 0x80000000u) ? ~bits : (bits ^ 0x80000000u);
    kl[i] = ((unsigned long long)mono << 32) | (unsigned)p;
  }
  __shared__ unsigned long long s_w[2][4];
  unsigned long long last = 0;
  for (int sel = 0; sel < NKN; sel++){
    unsigned long long mk[16];
#pragma unroll
    for (int i = 0; i < 16; i++)
      mk[i] = (kl[i] > last) ? kl[i] : 0xFFFFFFFFFFFFFFFFULL;
#pragma unroll
    for (int st = 8; st; st >>= 1)
      for (int i = 0; i < st; i++) mk[i] = u64min(mk[i], mk[i+st]);
    unsigned long long bk = mk[0];
    { unsigned long long a = shfl_down_u64(bk,16), c = shfl_down_u64(bk,32), d = shfl_down_u64(bk,48);
      bk = u64min(u64min(bk,a), u64min(c,d)); }
    { unsigned long long a = shfl_down_u64(bk,4),  c = shfl_down_u64(bk,8),  d = shfl_down_u64(bk,12);
      bk = u64min(u64min(bk,a), u64min(c,d)); }
    { unsigned long long a = shfl_down_u64(bk,1),  c = shfl_down_u64(bk,2),  d = shfl_down_u64(bk,3);
      bk = u64min(u64min(bk,a), u64min(c,d)); }
    const int par = sel & 1;
    if ((tid & 63) == 0) s_w[par][tid>>6] = bk;
    __syncthreads();
    unsigned long long m = u64min(u64min(s_w[par][0], s_w[par][1]),
                                  u64min(s_w[par][2], s_w[par][3]));
    last = m;
    if (tid == 0){
      unsigned hm = (unsigned)(m >> 32);
      unsigned bits = (hm & 0x80000000u) ? (hm ^ 0x80000000u) : ~hm;
      g_knn_idx[g*NKN + sel] = (int)(unsigned)m;
      g_knn_d2 [g*NKN + sel] = __uint_as_float(bits);
    }
  }
}

// ---------------------------------------------------------------- pos-embed MLP -> g_posb (f32)
__global__ __launch_bounds__(256) void k_posembed(
    const float* __restrict__ xyz,
    const float* __restrict__ w1, const float* __restrict__ b1, const float* __restrict__ bn1,
    const float* __restrict__ w2, const float* __restrict__ b2, const float* __restrict__ bn2){
  __shared__ float w1s[320], a1s[32], d1s[32], w2s[2048], a2s[64], d2s[64];
  const int t = threadIdx.x;
  for (int i = t; i < 320; i += 256) w1s[i] = w1[i];
  for (int i = t; i < 2048; i += 256) w2s[i] = w2[i];
  if (t < 32){
    float g = bn1[t], be = bn1[32+t], m = bn1[64+t], v = bn1[96+t];
    float a = g * rsqrtf(v + 1e-5f);
    a1s[t] = a; d1s[t] = b1[t]*a + (be - m*a);
  }
  if (t < 64){
    float g = bn2[t], be = bn2[64+t], m = bn2[128+t], v = bn2[192+t];
    float a = g * rsqrtf(v + 1e-5f);
    a2s[t] = a; d2s[t] = b2[t]*a + (be - m*a);
  }
  __syncthreads();
  const int row = blockIdx.x*256 + t;          // (b*512+s)*32 + k
  const int b = row >> 14;
  const int g = row >> 5;
  const float* X = xyz + (size_t)b * NPTS * 3;
  const int ci = g_fps_idx[g];
  const int ni = g_knn_idx[row];
  float c0 = X[3*ci], c1 = X[3*ci+1], c2 = X[3*ci+2];
  float n0 = X[3*ni], n1 = X[3*ni+1], n2 = X[3*ni+2];
  float feat[10] = {c0,c1,c2, n0,n1,n2, n0-c0,n1-c1,n2-c2, g_knn_d2[row]};
  float h[32];
  for (int o = 0; o < 32; o++){
    float acc = 0.f;
    for (int j = 0; j < 10; j++) acc += feat[j]*w1s[j*32+o];
    h[o] = fmaxf(acc*a1s[o] + d1s[o], 0.f);
  }
  float* xr = g_posb + (size_t)row * 64;
  for (int o = 0; o < 64; o++){
    float acc = 0.f;
    for (int j = 0; j < 32; j++) acc += h[j]*w2s[j*64+o];
    xr[o] = fmaxf(acc*a2s[o] + d2s[o], 0.f);
  }
}

// ---------------------------------------------------------------- Gram partials (K-split x4, symmetric)
// 288 blocks starved the machine (Occupancy 11%, 1 wave/SIMD -> latency-bound).
// K split into 4 chunks of 1024 -> 1152 blocks; partials summed by k_gred in
// fixed chunk order (deterministic; only f32 grouping of the K-sum changes).
__global__ __launch_bounds__(256) void k_gram(const float* __restrict__ points){
  const int b = blockIdx.y, ch = blockIdx.z;
  int ti = 0, rem = blockIdx.x;
  while (rem >= 8 - ti){ rem -= 8 - ti; ti++; }
  const int tj = ti + rem;
  const int i0 = ti * 64, j0 = tj * 64;
  __shared__ float As[32][68];
  __shared__ float Bs[32][68];
  const int t = threadIdx.x, tx = t & 15, ty = t >> 4;
  float acc[4][4] = {};
  const int kbeg = ch * 1024, kend = kbeg + 1024;
  for (int k0 = kbeg; k0 < kend; k0 += 32){
    {
      int r = t >> 2, kk = (t & 3) * 8;
      float ta[8], tb[8];
      load_gram8(points, b, i0+r, k0+kk, ta);
      load_gram8(points, b, j0+r, k0+kk, tb);
      for (int jj = 0; jj < 8; jj++){
        int k = kk + jj;
        int c = (r + (k & 24)) & 63;   // rotated column, conflict-free store
        As[k][c] = ta[jj]; Bs[k][c] = tb[jj];
      }
    }
    __syncthreads();
    for (int kk = 0; kk < 32; kk++){
      const int rot = kk & 24;
      const float4 a4 = *(const float4*)(&As[kk][(ty*4 + rot) & 63]);
      const float4 b4 = *(const float4*)(&Bs[kk][(tx*4 + rot) & 63]);
      const float ar[4] = {a4.x,a4.y,a4.z,a4.w};
      const float br[4] = {b4.x,b4.y,b4.z,b4.w};
      for (int ia = 0; ia < 4; ia++)
        for (int ib = 0; ib < 4; ib++) acc[ia][ib] += ar[ia]*br[ib];
    }
    __syncthreads();
  }
  float* C = g_gp + ((size_t)(ch*NB + b)) * NS * NS;
  for (int ia = 0; ia < 4; ia++){
    float4 o = {acc[ia][0], acc[ia][1], acc[ia][2], acc[ia][3]};
    *(float4*)(C + (size_t)(i0+ty*4+ia)*NS + j0 + tx*4) = o;
  }
  if (ti != tj){
    for (int ib = 0; ib < 4; ib++){
      float4 o = {acc[0][ib], acc[1][ib], acc[2][ib], acc[3][ib]};
      *(float4*)(C + (size_t)(j0+tx*4+ib)*NS + i0 + ty*4) = o;
    }
  }
}

// ---------------------------------------------------------------- gram chunk reduce: g_ga = sum of 4 partials
__global__ __launch_bounds__(256) void k_gred(){
  const size_t N = (size_t)NB * NS * NS;            // 2,097,152 floats
  size_t i = ((size_t)blockIdx.x*256 + threadIdx.x) * 4;
  float4 a = *(const float4*)(g_gp + i);
  float4 b = *(const float4*)(g_gp + N + i);
  float4 c = *(const float4*)(g_gp + 2*N + i);
  float4 d = *(const float4*)(g_gp + 3*N + i);
  float4 o = {((a.x + b.x) + c.x) + d.x,
              ((a.y + b.y) + c.y) + d.y,
              ((a.z + b.z) + c.z) + d.z,
              ((a.w + b.w) + c.w) + d.w};
  *(float4*)(g_ga + i) = o;
}

// ---------------------------------------------------------------- row softmax (in place)
__global__ __launch_bounds__(256) void k_softmax(){
  float* R = g_ga + (size_t)blockIdx.x * NS;
  const int t = threadIdx.x;
  float v0 = R[t], v1 = R[t+256];
  __shared__ float sm[4], ssum[4];
  float m = fmaxf(v0, v1);
  for (int off = 32; off; off >>= 1) m = fmaxf(m, __shfl_down(m, off));
  if ((t & 63) == 0) sm[t>>6] = m;
  __syncthreads();
  float mm = fmaxf(fmaxf(sm[0], sm[1]), fmaxf(sm[2], sm[3]));
  float e0 = expf(v0 - mm), e1 = expf(v1 - mm);
  float s = e0 + e1;
  for (int off = 32; off; off >>= 1) s += __shfl_down(s, off);
  if ((t & 63) == 0) ssum[t>>6] = s;
  __syncthreads();
  float inv = 1.0f / (ssum[0]+ssum[1]+ssum[2]+ssum[3]);
  R[t] = e0*inv; R[t+256] = e1*inv;
}

// ---------------------------------------------------------------- grp: ga @ flat, fused gamma*+x -> g_dsa[...,128:256]
__global__ __launch_bounds__(256) void k_grp(const float* __restrict__ points,
                                             const float* __restrict__ gam_g){
  const int b = blockIdx.y;
  const int s0 = (blockIdx.x >> 6) * 64, n0 = (blockIdx.x & 63) * 64;
  const float* G = g_ga + (size_t)b * NS * NS;
  __shared__ float As[32][68];
  __shared__ float Bs[32][68];
  const int t = threadIdx.x, tx = t & 15, ty = t >> 4;
  float acc[4][4] = {};
  for (int k0 = 0; k0 < NS; k0 += 32){
    {
      int r = t >> 2, kk = (t & 3) * 8;
      const float* pa = G + (size_t)(s0+r)*NS + k0 + kk;
      float4 v0 = *(const float4*)pa, v1 = *(const float4*)(pa+4);
      const float va[8] = {v0.x,v0.y,v0.z,v0.w,v1.x,v1.y,v1.z,v1.w};
      for (int jj = 0; jj < 8; jj++){
        int k = kk + jj;
        As[k][(r + (k & 24)) & 63] = va[jj];   // rotated column, conflict-free store
      }
      int k2 = t >> 3, c = (t & 7) * 8;
      float tb[8];
      load_flat8(points, b, k0+k2, n0+c, tb);
      float4 w0 = {tb[0],tb[1],tb[2],tb[3]}, w1 = {tb[4],tb[5],tb[6],tb[7]};
      *(float4*)(&Bs[k2][c])   = w0;
      *(float4*)(&Bs[k2][c+4]) = w1;
    }
    __syncthreads();
    for (int kk = 0; kk < 32; kk++){
      const float4 a4 = *(const float4*)(&As[kk][(ty*4 + (kk & 24)) & 63]);
      const float4 b4 = *(const float4*)(&Bs[kk][tx*4]);
      const float ar[4] = {a4.x,a4.y,a4.z,a4.w};
      const float br[4] = {b4.x,b4.y,b4.z,b4.w};
      for (int ia = 0; ia < 4; ia++)
        for (int ib = 0; ib < 4; ib++) acc[ia][ib] += ar[ia]*br[ib];
    }
    __syncthreads();
  }
  const float gmg = gam_g[0];
  const int n = n0 + tx*4;
  const int kq = n >> 7, dq = n & 127;
  for (int ia = 0; ia < 4; ia++){
    int s = s0 + ty*4 + ia;
    float4 xv = load_flat4(points, b, s, n);
    float4 o = {gmg*acc[ia][0]+xv.x, gmg*acc[ia][1]+xv.y,
                gmg*acc[ia][2]+xv.z, gmg*acc[ia][3]+xv.w};
    *(float4*)(g_dsa + ((size_t)((b*NS + s)*32 + kq))*256 + 128 + dq) = o;
  }
}

// ---------------------------------------------------------------- NSA: Q/K/V + softmax + PV -> g_dsa[...,0:128]
// Weight LDS staging (kills 32x per-block weight re-streaming through L2) with
// loop-unroll pinning to prevent register spill (round-8 lesson).
__global__ __launch_bounds__(256) void k_nsa(const float* __restrict__ points,
    const float* __restrict__ wq, const float* __restrict__ bq,
    const float* __restrict__ wk, const float* __restrict__ bk,
    const float* __restrict__ wv, const float* __restrict__ bv_,
    const float* __restrict__ nsa_g){
  const int g = blockIdx.y*512 + blockIdx.x;
  const int t = threadIdx.x, b = g >> 9;
  const int r = t >> 3, c = t & 7;
  __shared__ float xs[32][132];
  __shared__ float vs[32][132];          // float4 view: row stride 33
  __shared__ float qs[32][17], ks[32][17];
  __shared__ float at[32][33];
  __shared__ float wqs[2048];            // 128x16
  __shared__ float wks[2048];            // 128x16
  __shared__ float wvs[4096];            // 32x128 tile (reused 4x)
  // stage x row r (8 lanes of subgroup r cover the row) + wq/wk
  {
    float tmp[8];
    ldf8(g_posb + ((size_t)g*32 + r)*64 + c*8, tmp);
    for (int j = 0; j < 8; j++) xs[r][c*8+j] = tmp[j];
    int idx = g_knn_idx[g*32 + r];
    ldf8(points + ((size_t)b*NPTS + idx)*64 + c*8, tmp);
    for (int j = 0; j < 8; j++) xs[r][64+c*8+j] = tmp[j];
  }
  for (int i = t; i < 512; i += 256){
    ((float4*)wqs)[i] = ((const float4*)wq)[i];
    ((float4*)wks)[i] = ((const float4*)wk)[i];
  }
  __syncthreads();
  // Q/K projections from LDS (thread computes q[r][c], q[r][c+8], k[r][c], k[r][c+8])
  {
    float aq0 = bq[c], aq1 = bq[c+8], ak0 = bk[c], ak1 = bk[c+8];
#pragma unroll 8
    for (int j = 0; j < 128; j++){
      float xv = xs[r][j];
      aq0 += xv * wqs[j*16+c];
      aq1 += xv * wqs[j*16+c+8];
      ak0 += xv * wks[j*16+c];
      ak1 += xv * wks[j*16+c+8];
    }
    qs[r][c] = aq0; qs[r][c+8] = aq1; ks[r][c] = ak0; ks[r][c+8] = ak1;
  }
  // V projection, channels d = 32w + 4c + ii; wv streamed through LDS in 32-row tiles
  {
    const float4* bv4 = (const float4*)bv_;
    float4 va = bv4[c], vb = bv4[8+c], vc4 = bv4[16+c], vd = bv4[24+c];
#pragma unroll 1
    for (int t4 = 0; t4 < 4; t4++){
      if (t4) __syncthreads();           // prior tile's reads complete before overwrite
      for (int i = t; i < 1024; i += 256)
        ((float4*)wvs)[i] = ((const float4*)wv)[(size_t)t4*1024 + i];
      __syncthreads();
#pragma unroll 4
      for (int jl = 0; jl < 32; jl++){
        float xv = xs[r][t4*32 + jl];
        const float4* row = (const float4*)(wvs + jl*128);
        float4 w0 = row[c], w1 = row[8+c], w2 = row[16+c], w3 = row[24+c];
        va.x += xv*w0.x;  va.y += xv*w0.y;  va.z += xv*w0.z;  va.w += xv*w0.w;
        vb.x += xv*w1.x;  vb.y += xv*w1.y;  vb.z += xv*w1.z;  vb.w += xv*w1.w;
        vc4.x += xv*w2.x; vc4.y += xv*w2.y; vc4.z += xv*w2.z; vc4.w += xv*w2.w;
        vd.x += xv*w3.x;  vd.y += xv*w3.y;  vd.z += xv*w3.z;  vd.w += xv*w3.w;
      }
    }
    float4* vrow = (float4*)(&vs[r][0]);
    vrow[c] = va; vrow[8+c] = vb; vrow[16+c] = vc4; vrow[24+c] = vd;
  }
  __syncthreads();   // ks / vs cross-wave visibility
  // QK^T: s[jj] = q[r] . k[4c+jj]
  float p0, p1, p2, p3;
  {
    float s[4];
    for (int jj = 0; jj < 4; jj++){
      int j = 4*c + jj; float acc = 0.f;
      for (int cc = 0; cc < 16; cc++) acc += qs[r][cc] * ks[j][cc];
      s[jj] = acc;
    }
    // row softmax across the 8-lane subgroup (all lanes active)
    float m = fmaxf(fmaxf(s[0], s[1]), fmaxf(s[2], s[3]));
    m = fmaxf(m, __shfl_xor(m, 1));
    m = fmaxf(m, __shfl_xor(m, 2));
    m = fmaxf(m, __shfl_xor(m, 4));
    float e0 = expf(s[0]-m), e1 = expf(s[1]-m), e2 = expf(s[2]-m), e3 = expf(s[3]-m);
    float sum = ((e0 + e1) + (e2 + e3));
    sum += __shfl_xor(sum, 1);
    sum += __shfl_xor(sum, 2);
    sum += __shfl_xor(sum, 4);
    float inv = 1.0f / sum;
    p0 = e0*inv; p1 = e1*inv; p2 = e2*inv; p3 = e3*inv;
    at[r][4*c+0] = p0; at[r][4*c+1] = p1; at[r][4*c+2] = p2; at[r][4*c+3] = p3;
  }
  // PV + gamma*.+x residual (at row r is wave-local; vs synced above)
  {
    float4 a0 = {0,0,0,0}, a1 = {0,0,0,0}, a2 = {0,0,0,0}, a3 = {0,0,0,0};
    for (int j = 0; j < 32; j++){
      float a = at[r][j];
      const float4* vrow = (const float4*)(&vs[j][0]);
      float4 w0 = vrow[c], w1 = vrow[8+c], w2 = vrow[16+c], w3 = vrow[24+c];
      a0.x += a*w0.x; a0.y += a*w0.y; a0.z += a*w0.z; a0.w += a*w0.w;
      a1.x += a*w1.x; a1.y += a*w1.y; a1.z += a*w1.z; a1.w += a*w1.w;
      a2.x += a*w2.x; a2.y += a*w2.y; a2.z += a*w2.z; a2.w += a*w2.w;
      a3.x += a*w3.x; a3.y += a*w3.y; a3.z += a*w3.z; a3.w += a*w3.w;
    }
    const float gmn = nsa_g[0];
    float* dst = g_dsa + ((size_t)g*32 + r)*256;
    float4 x0 = *(const float4*)(&xs[r][ 0+4*c]);
    float4 x1 = *(const float4*)(&xs[r][32+4*c]);
    float4 x2 = *(const float4*)(&xs[r][64+4*c]);
    float4 x3 = *(const float4*)(&xs[r][96+4*c]);
    float4 o0 = {gmn*a0.x+x0.x, gmn*a0.y+x0.y, gmn*a0.z+x0.z, gmn*a0.w+x0.w};
    float4 o1 = {gmn*a1.x+x1.x, gmn*a1.y+x1.y, gmn*a1.z+x1.z, gmn*a1.w+x1.w};
    float4 o2 = {gmn*a2.x+x2.x, gmn*a2.y+x2.y, gmn*a2.z+x2.z, gmn*a2.w+x2.w};
    float4 o3 = {gmn*a3.x+x3.x, gmn*a3.y+x3.y, gmn*a3.z+x3.z, gmn*a3.w+x3.w};
    *(float4*)(dst +  0 + 4*c) = o0;
    *(float4*)(dst + 32 + 4*c) = o1;
    *(float4*)(dst + 64 + 4*c) = o2;
    *(float4*)(dst + 96 + 4*c) = o3;
  }
}

// ---------------------------------------------------------------- cat MLP + shortcut + maxpool -> out
// Round-3 structure (measured best: 530us). 256 threads, separate hs buffer.
__global__ __launch_bounds__(256) void k_mlp(const float* __restrict__ points,
    const float* __restrict__ w1, const float* __restrict__ b1, const float* __restrict__ bn1,
    const float* __restrict__ w2, const float* __restrict__ b2, const float* __restrict__ bn2,
    const float* __restrict__ wsc, const float* __restrict__ bsc, const float* __restrict__ bnsc,
    float* __restrict__ out){
  const int g = blockIdx.y*512 + blockIdx.x;
  const int t = threadIdx.x, b = g >> 9;
  __shared__ float ds[32][260];
  __shared__ float hs[32][260];
  __shared__ float ps[32][68];
  __shared__ float a1s[256], d1s[256];
  __shared__ float red[256];
  for (int i = t; i < 2048; i += 256){
    int r = i >> 6, c = (i & 63) * 4;
    *(float4*)(&ds[r][c]) = *(const float4*)(g_dsa + ((size_t)g*32 + r)*256 + c);
  }
  for (int i = t; i < 512; i += 256){
    int r = i >> 4, c = (i & 15) * 4;
    int idx = g_knn_idx[g*32 + r];
    *(float4*)(&ps[r][c]) = *(const float4*)(points + ((size_t)b*NPTS + idx)*64 + c);
  }
  {
    float gg2 = bn1[t], be = bn1[256+t], m = bn1[512+t], v = bn1[768+t];
    float a = gg2 * rsqrtf(v + 1e-5f);
    a1s[t] = a; d1s[t] = b1[t]*a + (be - m*a);
  }
  __syncthreads();
  // C1: h = relu(bn1(dsa @ W1 + b1))
  {
    const int kg = t >> 6, c0 = (t & 63) * 4;
    float acc[8][4] = {};
    for (int j = 0; j < 256; j += 4){
      float wvv[4][4];
      for (int jj = 0; jj < 4; jj++){
        float4 wrow = *(const float4*)(w1 + (j+jj)*256 + c0);
        wvv[jj][0] = wrow.x; wvv[jj][1] = wrow.y; wvv[jj][2] = wrow.z; wvv[jj][3] = wrow.w;
      }
      for (int r = 0; r < 8; r++){
        const float4 d4 = *(const float4*)(&ds[kg*8+r][j]);
        const float dr[4] = {d4.x, d4.y, d4.z, d4.w};
        for (int jj = 0; jj < 4; jj++)
          for (int i = 0; i < 4; i++) acc[r][i] += dr[jj]*wvv[jj][i];
      }
    }
    for (int r = 0; r < 8; r++){
      float4 o;
      o.x = fmaxf(acc[r][0]*a1s[c0+0] + d1s[c0+0], 0.f);
      o.y = fmaxf(acc[r][1]*a1s[c0+1] + d1s[c0+1], 0.f);
      o.z = fmaxf(acc[r][2]*a1s[c0+2] + d1s[c0+2], 0.f);
      o.w = fmaxf(acc[r][3]*a1s[c0+3] + d1s[c0+3], 0.f);
      *(float4*)(&hs[kg*8+r][c0]) = o;
    }
  }
  __syncthreads();
  // C2: layer 2 + shortcut + relu + max over k
  {
    const int c = t & 127, kh = t >> 7;
    float g2 = bn2[c], be2 = bn2[128+c], m2 = bn2[256+c], v2 = bn2[384+c];
    float a2 = g2 * rsqrtf(v2 + 1e-5f);
    float d2v = b2[c]*a2 + (be2 - m2*a2);
    float gsc = bnsc[c], besc = bnsc[128+c], msc = bnsc[256+c], vsc = bnsc[384+c];
    float asc = gsc * rsqrtf(vsc + 1e-5f);
    float dscv = bsc[c]*asc + (besc - msc*asc);
    float accm[16] = {};
    for (int j = 0; j < 256; j += 4){
      float w0 = w2[j*128+c], w1v = w2[(j+1)*128+c];
      float w2v = w2[(j+2)*128+c], w3 = w2[(j+3)*128+c];
      for (int r = 0; r < 16; r++){
        const float4 h4 = *(const float4*)(&hs[kh*16+r][j]);
        accm[r] += h4.x*w0; accm[r] += h4.y*w1v; accm[r] += h4.z*w2v; accm[r] += h4.w*w3;
      }
    }
    float accs[16] = {};
    for (int j = 0; j < 64; j += 4){
      float w0 = wsc[j*128+c], w1v = wsc[(j+1)*128+c];
      float w2v = wsc[(j+2)*128+c], w3 = wsc[(j+3)*128+c];
      for (int r = 0; r < 16; r++){
        const float4 p4 = *(const float4*)(&ps[kh*16+r][j]);
        accs[r] += p4.x*w0; accs[r] += p4.y*w1v; accs[r] += p4.z*w2v; accs[r] += p4.w*w3;
      }
    }
    float mx = -1e30f;
    for (int r = 0; r < 16; r++){
      float mainv = accm[r]*a2 + d2v;
      float scv = fmaxf(accs[r]*asc + dscv, 0.f);
      mx = fmaxf(mx, fmaxf(mainv + scv, 0.f));
    }
    red[t] = mx;
  }
  __syncthreads();
  if (t < 128){
    float m = fmaxf(red[t], red[t+128]);
    out[12288 + (size_t)g*128 + t] = m;
  }
}

// ----------------------------------------------------------------
extern "C" void kernel_launch(void* const* d_in, const int* in_sizes, int n_in,
                              void* d_out, int out_size, void* d_ws, size_t ws_size,
                              hipStream_t stream){
  (void)in_sizes; (void)n_in; (void)d_ws; (void)ws_size; (void)out_size;
  const float* xyz      = (const float*)d_in[0];
  const float* points   = (const float*)d_in[1];
  const int*   fstart   = (const int*)  d_in[2];
  const float* pos_w1   = (const float*)d_in[3];
  const float* pos_b1   = (const float*)d_in[4];
  const float* pos_bn1  = (const float*)d_in[5];
  const float* pos_w2   = (const float*)d_in[6];
  const float* pos_b2   = (const float*)d_in[7];
  const float* pos_bn2  = (const float*)d_in[8];
  const float* nsa_wq   = (const float*)d_in[9];
  const float* nsa_bq   = (const float*)d_in[10];
  const float* nsa_wk   = (const float*)d_in[11];
  const float* nsa_bk   = (const float*)d_in[12];
  const float* nsa_wv   = (const float*)d_in[13];
  const float* nsa_bv   = (const float*)d_in[14];
  const float* nsa_g    = (const float*)d_in[15];
  const float* gam_g    = (const float*)d_in[16];
  const float* cat_w1   = (const float*)d_in[17];
  const float* cat_b1   = (const float*)d_in[18];
  const float* cat_bn1  = (const float*)d_in[19];
  const float* cat_w2   = (const float*)d_in[20];
  const float* cat_b2   = (const float*)d_in[21];
  const float* cat_bn2  = (const float*)d_in[22];
  const float* sc_w     = (const float*)d_in[23];
  const float* sc_b     = (const float*)d_in[24];
  const float* sc_bn    = (const float*)d_in[25];
  float* out = (float*)d_out;   // output is float32

  k_fps     <<<NB, 256, 0, stream>>>(xyz, fstart, out);
  k_knn     <<<NB*NS, 256, 0, stream>>>(xyz);
  k_posembed<<<512, 256, 0, stream>>>(xyz, pos_w1, pos_b1, pos_bn1, pos_w2, pos_b2, pos_bn2);
  k_gram    <<<dim3(36, NB, 4), 256, 0, stream>>>(points);
  k_gred    <<<2048, 256, 0, stream>>>();
  k_softmax <<<NB*NS, 256, 0, stream>>>();
  k_grp     <<<dim3(512, NB), 256, 0, stream>>>(points, gam_g);
  k_nsa     <<<dim3(512, NB), 256, 0, stream>>>(points, nsa_wq, nsa_bq, nsa_wk, nsa_bk,
                                                nsa_wv, nsa_bv, nsa_g);
  k_mlp     <<<dim3(512, NB), 256, 0, stream>>>(points, cat_w1, cat_b1, cat_bn1,
                                                cat_w2, cat_b2, cat_bn2,
                                                sc_w, sc_b, sc_bn, out);
}

// Round 11
// 1679.901 us; speedup vs baseline: 3.1021x; 1.0352x over previous
//
#include <hip/hip_runtime.h>
#include <stdint.h>
#include <float.h>

typedef unsigned int uint;

#define NB 8
#define NPTS 4096
#define NS 512
#define NKN 32

// ---- static device scratch (~210 MB, allocated at module load; fully rewritten each call)
__device__ int   g_fps_idx[NB*NS];
__device__ int   g_knn_idx[NB*NS*NKN];
__device__ float g_knn_d2 [NB*NS*NKN];
__device__ float g_posb   [(size_t)NB*NS*NKN*64];    //  33.5 MB
__device__ float g_ga     [(size_t)NB*NS*NS];        //   8.4 MB
__device__ float g_gp     [(size_t)4*NB*NS*NS];      //  33.5 MB gram K-chunk partials
__device__ float g_dsa    [(size_t)NB*NS*NKN*256];   // 134 MB  [group*32+k][256] = [nei|grp]

__device__ __forceinline__ unsigned long long shfl_down_u64(unsigned long long v, int off){
  int lo = __shfl_down((int)(unsigned)v, off);
  int hi = __shfl_down((int)(unsigned)(v >> 32), off);
  return ((unsigned long long)(unsigned)hi << 32) | (unsigned)lo;
}
__device__ __forceinline__ unsigned long long u64max(unsigned long long a, unsigned long long b){
  return a > b ? a : b;
}
__device__ __forceinline__ unsigned long long u64min(unsigned long long a, unsigned long long b){
  return a < b ? a : b;
}
__device__ __forceinline__ void ldf8(const float* p, float* d){
  float4 a = *(const float4*)p, b = *(const float4*)(p+4);
  d[0]=a.x; d[1]=a.y; d[2]=a.z; d[3]=a.w; d[4]=b.x; d[5]=b.y; d[6]=b.z; d[7]=b.w;
}
// robust start read: int32 (start[b]) vs int64 (start[2b]; high words zero since values<4096)
__device__ __forceinline__ int read_start(const int* __restrict__ start, int b){
  int w1 = start[1], w3 = start[3], w5 = start[5], w7 = start[7];
  bool is64 = ((w1 | w3 | w5 | w7) == 0);
  int v = is64 ? start[2*b] : start[b];
  return v & (NPTS - 1);
}

// flat column order: n = k*128 + d, d<64 -> posb, d>=64 -> points gather
__device__ __forceinline__ void load_flat8(const float* __restrict__ points,
                                           int b, int row, int n, float* d){
  const int k = n >> 7, col = n & 63;
  if (n & 64){
    const int idx = g_knn_idx[((b << 9) + row)*32 + k];
    ldf8(points + (((size_t)b << 12) + idx)*64 + col, d);
  } else {
    ldf8(g_posb + (((size_t)((b << 9) + row))*32 + k)*64 + col, d);
  }
}
__device__ __forceinline__ float4 load_flat4(const float* __restrict__ points,
                                             int b, int row, int n){
  const int k = n >> 7, d = n & 127;
  if (d & 64){
    const int idx = g_knn_idx[((b << 9) + row)*32 + k];
    return *(const float4*)(points + (((size_t)b << 12) + idx)*64 + (d & 63));
  } else {
    return *(const float4*)(g_posb + (((size_t)((b << 9) + row))*32 + k)*64 + d);
  }
}
// reorganized order for Gram only: kc in [0,2048) pos (k-major), [2048,4096) pts
__device__ __forceinline__ void load_gram8(const float* __restrict__ points,
                                           int b, int row, int kc, float* d){
  if (kc < 2048){
    ldf8(g_posb + ((size_t)((b << 9) + row))*2048 + kc, d);
  } else {
    const int kc2 = kc - 2048, kg = kc2 >> 6, col = kc2 & 63;
    const int idx = g_knn_idx[((b << 9) + row)*32 + kg];
    ldf8(points + (((size_t)b << 12) + idx)*64 + col, d);
  }
}

// ---------------------------------------------------------------- FPS (f32 running-max + packed-key shuffle, 256 thr)
// Per-step: running (dist, i) max inside the distance loop (3 inst/elem; strict >
// keeps lower i = lower idx, matching the packed key's tie-break), pack to u64
// ONCE, then the radix-4 u64 shuffle cascade. Replaces the 15-node u64 tree
// (~75 inst -> ~50 inst per step). Bit-exact selection vs round-10.
__global__ __launch_bounds__(256) void k_fps(const float* __restrict__ xyz,
                                             const int* __restrict__ start,
                                             float* __restrict__ center_out){
#pragma clang fp contract(off)
  const int b = blockIdx.x, tid = threadIdx.x;
  const float* X = xyz + (size_t)b * NPTS * 3;
  __shared__ float sx[NPTS], sy[NPTS], sz[NPTS];
  for (int p = tid; p < NPTS; p += 256){
    sx[p] = X[3*p]; sy[p] = X[3*p+1]; sz[p] = X[3*p+2];
  }
  __shared__ int s_start0;
  if (tid == 0) s_start0 = read_start(start, b);
  __syncthreads();
  float px[16], py[16], pz[16], dist[16];
  for (int i = 0; i < 16; i++){
    int p = tid*16 + i;
    px[i] = sx[p]; py[i] = sy[p]; pz[i] = sz[p];
    dist[i] = 1e10f;
  }
  __shared__ unsigned long long s_k[2][4];
  int cur = s_start0;
  for (int t = 0; t < NS; t++){
    if (tid == 0){
      g_fps_idx[b*NS + t] = cur;
      center_out[(size_t)(b*NS + t)*3 + 0] = sx[cur];
      center_out[(size_t)(b*NS + t)*3 + 1] = sy[cur];
      center_out[(size_t)(b*NS + t)*3 + 2] = sz[cur];
    }
    const float cx = sx[cur], cy = sy[cur], cz = sz[cur];
    float bv = -1.0f; int bi = 0;
#pragma unroll
    for (int i = 0; i < 16; i++){
      float dx = px[i]-cx, dy = py[i]-cy, dz = pz[i]-cz;
      float d = ((dx*dx) + (dy*dy)) + (dz*dz);
      dist[i] = fminf(dist[i], d);
      if (dist[i] > bv){ bv = dist[i]; bi = i; }   // strict >: keeps lower i (= lower idx)
    }
    unsigned long long bk = ((unsigned long long)__float_as_uint(bv) << 32)
                          | (unsigned)(NPTS-1 - (tid*16 + bi));
    { unsigned long long a = shfl_down_u64(bk,16), c = shfl_down_u64(bk,32), d = shfl_down_u64(bk,48);
      bk = u64max(u64max(bk,a), u64max(c,d)); }
    { unsigned long long a = shfl_down_u64(bk,4),  c = shfl_down_u64(bk,8),  d = shfl_down_u64(bk,12);
      bk = u64max(u64max(bk,a), u64max(c,d)); }
    { unsigned long long a = shfl_down_u64(bk,1),  c = shfl_down_u64(bk,2),  d = shfl_down_u64(bk,3);
      bk = u64max(u64max(bk,a), u64max(c,d)); }
    const int par = t & 1;
    if ((tid & 63) == 0) s_k[par][tid>>6] = bk;
    __syncthreads();
    unsigned long long m = u64max(u64max(s_k[par][0], s_k[par][1]),
                                  u64max(s_k[par][2], s_k[par][3]));
    cur = NPTS-1 - (int)(unsigned)m;
  }
}

// ---------------------------------------------------------------- KNN top-32 (f32 packed-key, 1 barrier/sel)
__global__ __launch_bounds__(256) void k_knn(const float* __restrict__ xyz){
#pragma clang fp contract(off)
  const int g = blockIdx.x;            // b*512 + s
  const int b = g >> 9;
  const int tid = threadIdx.x;
  const float* X = xyz + (size_t)b * NPTS * 3;
  const int cidx = g_fps_idx[g];
  const float cx = X[3*cidx], cy = X[3*cidx+1], cz = X[3*cidx+2];
  const float cs = ((cx*cx) + (cy*cy)) + (cz*cz);
  unsigned long long kl[16];
#pragma unroll
  for (int i = 0; i < 16; i++){
    int p = tid*16 + i;
    float x = X[3*p], y = X[3*p+1], z = X[3*p+2];
    float xs2 = ((x*x) + (y*y)) + (z*z);
    float dt  = ((cx*x) + (cy*y)) + (cz*z);
    float d   = (cs + xs2) - 2.0f*dt;
    unsigned bits = __float_as_uint(d);
    unsigned mono = (bits & 0x80000000u) ? ~bits : (bits ^ 0x80000000u);
    kl[i] = ((unsigned long long)mono << 32) | (unsigned)p;
  }
  __shared__ unsigned long long s_w[2][4];
  unsigned long long last = 0;
  for (int sel = 0; sel < NKN; sel++){
    unsigned long long mk[16];
#pragma unroll
    for (int i = 0; i < 16; i++)
      mk[i] = (kl[i] > last) ? kl[i] : 0xFFFFFFFFFFFFFFFFULL;
#pragma unroll
    for (int st = 8; st; st >>= 1)
      for (int i = 0; i < st; i++) mk[i] = u64min(mk[i], mk[i+st]);
    unsigned long long bk = mk[0];
    { unsigned long long a = shfl_down_u64(bk,16), c = shfl_down_u64(bk,32), d = shfl_down_u64(bk,48);
      bk = u64min(u64min(bk,a), u64min(c,d)); }
    { unsigned long long a = shfl_down_u64(bk,4),  c = shfl_down_u64(bk,8),  d = shfl_down_u64(bk,12);
      bk = u64min(u64min(bk,a), u64min(c,d)); }
    { unsigned long long a = shfl_down_u64(bk,1),  c = shfl_down_u64(bk,2),  d = shfl_down_u64(bk,3);
      bk = u64min(u64min(bk,a), u64min(c,d)); }
    const int par = sel & 1;
    if ((tid & 63) == 0) s_w[par][tid>>6] = bk;
    __syncthreads();
    unsigned long long m = u64min(u64min(s_w[par][0], s_w[par][1]),
                                  u64min(s_w[par][2], s_w[par][3]));
    last = m;
    if (tid == 0){
      unsigned hm = (unsigned)(m >> 32);
      unsigned bits = (hm & 0x80000000u) ? (hm ^ 0x80000000u) : ~hm;
      g_knn_idx[g*NKN + sel] = (int)(unsigned)m;
      g_knn_d2 [g*NKN + sel] = __uint_as_float(bits);
    }
  }
}

// ---------------------------------------------------------------- pos-embed MLP -> g_posb (f32)
__global__ __launch_bounds__(256) void k_posembed(
    const float* __restrict__ xyz,
    const float* __restrict__ w1, const float* __restrict__ b1, const float* __restrict__ bn1,
    const float* __restrict__ w2, const float* __restrict__ b2, const float* __restrict__ bn2){
  __shared__ float w1s[320], a1s[32], d1s[32], w2s[2048], a2s[64], d2s[64];
  const int t = threadIdx.x;
  for (int i = t; i < 320; i += 256) w1s[i] = w1[i];
  for (int i = t; i < 2048; i += 256) w2s[i] = w2[i];
  if (t < 32){
    float g = bn1[t], be = bn1[32+t], m = bn1[64+t], v = bn1[96+t];
    float a = g * rsqrtf(v + 1e-5f);
    a1s[t] = a; d1s[t] = b1[t]*a + (be - m*a);
  }
  if (t < 64){
    float g = bn2[t], be = bn2[64+t], m = bn2[128+t], v = bn2[192+t];
    float a = g * rsqrtf(v + 1e-5f);
    a2s[t] = a; d2s[t] = b2[t]*a + (be - m*a);
  }
  __syncthreads();
  const int row = blockIdx.x*256 + t;          // (b*512+s)*32 + k
  const int b = row >> 14;
  const int g = row >> 5;
  const float* X = xyz + (size_t)b * NPTS * 3;
  const int ci = g_fps_idx[g];
  const int ni = g_knn_idx[row];
  float c0 = X[3*ci], c1 = X[3*ci+1], c2 = X[3*ci+2];
  float n0 = X[3*ni], n1 = X[3*ni+1], n2 = X[3*ni+2];
  float feat[10] = {c0,c1,c2, n0,n1,n2, n0-c0,n1-c1,n2-c2, g_knn_d2[row]};
  float h[32];
  for (int o = 0; o < 32; o++){
    float acc = 0.f;
    for (int j = 0; j < 10; j++) acc += feat[j]*w1s[j*32+o];
    h[o] = fmaxf(acc*a1s[o] + d1s[o], 0.f);
  }
  float* xr = g_posb + (size_t)row * 64;
  for (int o = 0; o < 64; o++){
    float acc = 0.f;
    for (int j = 0; j < 32; j++) acc += h[j]*w2s[j*64+o];
    xr[o] = fmaxf(acc*a2s[o] + d2s[o], 0.f);
  }
}

// ---------------------------------------------------------------- Gram partials (K-split x4, symmetric)
__global__ __launch_bounds__(256) void k_gram(const float* __restrict__ points){
  const int b = blockIdx.y, ch = blockIdx.z;
  int ti = 0, rem = blockIdx.x;
  while (rem >= 8 - ti){ rem -= 8 - ti; ti++; }
  const int tj = ti + rem;
  const int i0 = ti * 64, j0 = tj * 64;
  __shared__ float As[32][68];
  __shared__ float Bs[32][68];
  const int t = threadIdx.x, tx = t & 15, ty = t >> 4;
  float acc[4][4] = {};
  const int kbeg = ch * 1024, kend = kbeg + 1024;
  for (int k0 = kbeg; k0 < kend; k0 += 32){
    {
      int r = t >> 2, kk = (t & 3) * 8;
      float ta[8], tb[8];
      load_gram8(points, b, i0+r, k0+kk, ta);
      load_gram8(points, b, j0+r, k0+kk, tb);
      for (int jj = 0; jj < 8; jj++){
        int k = kk + jj;
        int c = (r + (k & 24)) & 63;   // rotated column, conflict-free store
        As[k][c] = ta[jj]; Bs[k][c] = tb[jj];
      }
    }
    __syncthreads();
    for (int kk = 0; kk < 32; kk++){
      const int rot = kk & 24;
      const float4 a4 = *(const float4*)(&As[kk][(ty*4 + rot) & 63]);
      const float4 b4 = *(const float4*)(&Bs[kk][(tx*4 + rot) & 63]);
      const float ar[4] = {a4.x,a4.y,a4.z,a4.w};
      const float br[4] = {b4.x,b4.y,b4.z,b4.w};
      for (int ia = 0; ia < 4; ia++)
        for (int ib = 0; ib < 4; ib++) acc[ia][ib] += ar[ia]*br[ib];
    }
    __syncthreads();
  }
  float* C = g_gp + ((size_t)(ch*NB + b)) * NS * NS;
  for (int ia = 0; ia < 4; ia++){
    float4 o = {acc[ia][0], acc[ia][1], acc[ia][2], acc[ia][3]};
    *(float4*)(C + (size_t)(i0+ty*4+ia)*NS + j0 + tx*4) = o;
  }
  if (ti != tj){
    for (int ib = 0; ib < 4; ib++){
      float4 o = {acc[0][ib], acc[1][ib], acc[2][ib], acc[3][ib]};
      *(float4*)(C + (size_t)(j0+tx*4+ib)*NS + i0 + ty*4) = o;
    }
  }
}

// ---------------------------------------------------------------- fused gram-reduce + row softmax -> g_ga
// One block per Gram row: sum the 4 K-chunk partials in fixed order (identical
// grouping to the old k_gred), then the identical softmax. Saves a full
// read+write pass over g_ga and one launch. Bit-exact vs k_gred + k_softmax.
__global__ __launch_bounds__(256) void k_gsm(){
  const size_t N = (size_t)NB * NS * NS;
  const size_t base = (size_t)blockIdx.x * NS;
  const int t = threadIdx.x;
  float v0, v1;
  {
    float a0 = g_gp[base + t],       b0 = g_gp[N + base + t];
    float c0 = g_gp[2*N + base + t], d0 = g_gp[3*N + base + t];
    v0 = ((a0 + b0) + c0) + d0;
    float a1 = g_gp[base + t + 256],       b1 = g_gp[N + base + t + 256];
    float c1 = g_gp[2*N + base + t + 256], d1 = g_gp[3*N + base + t + 256];
    v1 = ((a1 + b1) + c1) + d1;
  }
  __shared__ float sm[4], ssum[4];
  float m = fmaxf(v0, v1);
  for (int off = 32; off; off >>= 1) m = fmaxf(m, __shfl_down(m, off));
  if ((t & 63) == 0) sm[t>>6] = m;
  __syncthreads();
  float mm = fmaxf(fmaxf(sm[0], sm[1]), fmaxf(sm[2], sm[3]));
  float e0 = expf(v0 - mm), e1 = expf(v1 - mm);
  float s = e0 + e1;
  for (int off = 32; off; off >>= 1) s += __shfl_down(s, off);
  if ((t & 63) == 0) ssum[t>>6] = s;
  __syncthreads();
  float inv = 1.0f / (ssum[0]+ssum[1]+ssum[2]+ssum[3]);
  g_ga[base + t] = e0*inv;
  g_ga[base + t + 256] = e1*inv;
}

// ---------------------------------------------------------------- grp: ga @ flat, fused gamma*+x -> g_dsa[...,128:256]
__global__ __launch_bounds__(256) void k_grp(const float* __restrict__ points,
                                             const float* __restrict__ gam_g){
  const int b = blockIdx.y;
  const int s0 = (blockIdx.x >> 6) * 64, n0 = (blockIdx.x & 63) * 64;
  const float* G = g_ga + (size_t)b * NS * NS;
  __shared__ float As[32][68];
  __shared__ float Bs[32][68];
  const int t = threadIdx.x, tx = t & 15, ty = t >> 4;
  float acc[4][4] = {};
  for (int k0 = 0; k0 < NS; k0 += 32){
    {
      int r = t >> 2, kk = (t & 3) * 8;
      const float* pa = G + (size_t)(s0+r)*NS + k0 + kk;
      float4 v0 = *(const float4*)pa, v1 = *(const float4*)(pa+4);
      const float va[8] = {v0.x,v0.y,v0.z,v0.w,v1.x,v1.y,v1.z,v1.w};
      for (int jj = 0; jj < 8; jj++){
        int k = kk + jj;
        As[k][(r + (k & 24)) & 63] = va[jj];   // rotated column, conflict-free store
      }
      int k2 = t >> 3, c = (t & 7) * 8;
      float tb[8];
      load_flat8(points, b, k0+k2, n0+c, tb);
      float4 w0 = {tb[0],tb[1],tb[2],tb[3]}, w1 = {tb[4],tb[5],tb[6],tb[7]};
      *(float4*)(&Bs[k2][c])   = w0;
      *(float4*)(&Bs[k2][c+4]) = w1;
    }
    __syncthreads();
    for (int kk = 0; kk < 32; kk++){
      const float4 a4 = *(const float4*)(&As[kk][(ty*4 + (kk & 24)) & 63]);
      const float4 b4 = *(const float4*)(&Bs[kk][tx*4]);
      const float ar[4] = {a4.x,a4.y,a4.z,a4.w};
      const float br[4] = {b4.x,b4.y,b4.z,b4.w};
      for (int ia = 0; ia < 4; ia++)
        for (int ib = 0; ib < 4; ib++) acc[ia][ib] += ar[ia]*br[ib];
    }
    __syncthreads();
  }
  const float gmg = gam_g[0];
  const int n = n0 + tx*4;
  const int kq = n >> 7, dq = n & 127;
  for (int ia = 0; ia < 4; ia++){
    int s = s0 + ty*4 + ia;
    float4 xv = load_flat4(points, b, s, n);
    float4 o = {gmg*acc[ia][0]+xv.x, gmg*acc[ia][1]+xv.y,
                gmg*acc[ia][2]+xv.z, gmg*acc[ia][3]+xv.w};
    *(float4*)(g_dsa + ((size_t)((b*NS + s)*32 + kq))*256 + 128 + dq) = o;
  }
}

// ---------------------------------------------------------------- NSA: Q/K/V + softmax + PV -> g_dsa[...,0:128]
// Weight LDS staging (kills 32x per-block weight re-streaming through L2) with
// loop-unroll pinning to prevent register spill (round-8 lesson).
__global__ __launch_bounds__(256) void k_nsa(const float* __restrict__ points,
    const float* __restrict__ wq, const float* __restrict__ bq,
    const float* __restrict__ wk, const float* __restrict__ bk,
    const float* __restrict__ wv, const float* __restrict__ bv_,
    const float* __restrict__ nsa_g){
  const int g = blockIdx.y*512 + blockIdx.x;
  const int t = threadIdx.x, b = g >> 9;
  const int r = t >> 3, c = t & 7;
  __shared__ float xs[32][132];
  __shared__ float vs[32][132];          // float4 view: row stride 33
  __shared__ float qs[32][17], ks[32][17];
  __shared__ float at[32][33];
  __shared__ float wqs[2048];            // 128x16
  __shared__ float wks[2048];            // 128x16
  __shared__ float wvs[4096];            // 32x128 tile (reused 4x)
  // stage x row r (8 lanes of subgroup r cover the row) + wq/wk
  {
    float tmp[8];
    ldf8(g_posb + ((size_t)g*32 + r)*64 + c*8, tmp);
    for (int j = 0; j < 8; j++) xs[r][c*8+j] = tmp[j];
    int idx = g_knn_idx[g*32 + r];
    ldf8(points + ((size_t)b*NPTS + idx)*64 + c*8, tmp);
    for (int j = 0; j < 8; j++) xs[r][64+c*8+j] = tmp[j];
  }
  for (int i = t; i < 512; i += 256){
    ((float4*)wqs)[i] = ((const float4*)wq)[i];
    ((float4*)wks)[i] = ((const float4*)wk)[i];
  }
  __syncthreads();
  // Q/K projections from LDS (thread computes q[r][c], q[r][c+8], k[r][c], k[r][c+8])
  {
    float aq0 = bq[c], aq1 = bq[c+8], ak0 = bk[c], ak1 = bk[c+8];
#pragma unroll 8
    for (int j = 0; j < 128; j++){
      float xv = xs[r][j];
      aq0 += xv * wqs[j*16+c];
      aq1 += xv * wqs[j*16+c+8];
      ak0 += xv * wks[j*16+c];
      ak1 += xv * wks[j*16+c+8];
    }
    qs[r][c] = aq0; qs[r][c+8] = aq1; ks[r][c] = ak0; ks[r][c+8] = ak1;
  }
  // V projection, channels d = 32w + 4c + ii; wv streamed through LDS in 32-row tiles
  {
    const float4* bv4 = (const float4*)bv_;
    float4 va = bv4[c], vb = bv4[8+c], vc4 = bv4[16+c], vd = bv4[24+c];
#pragma unroll 1
    for (int t4 = 0; t4 < 4; t4++){
      if (t4) __syncthreads();           // prior tile's reads complete before overwrite
      for (int i = t; i < 1024; i += 256)
        ((float4*)wvs)[i] = ((const float4*)wv)[(size_t)t4*1024 + i];
      __syncthreads();
#pragma unroll 4
      for (int jl = 0; jl < 32; jl++){
        float xv = xs[r][t4*32 + jl];
        const float4* row = (const float4*)(wvs + jl*128);
        float4 w0 = row[c], w1 = row[8+c], w2 = row[16+c], w3 = row[24+c];
        va.x += xv*w0.x;  va.y += xv*w0.y;  va.z += xv*w0.z;  va.w += xv*w0.w;
        vb.x += xv*w1.x;  vb.y += xv*w1.y;  vb.z += xv*w1.z;  vb.w += xv*w1.w;
        vc4.x += xv*w2.x; vc4.y += xv*w2.y; vc4.z += xv*w2.z; vc4.w += xv*w2.w;
        vd.x += xv*w3.x;  vd.y += xv*w3.y;  vd.z += xv*w3.z;  vd.w += xv*w3.w;
      }
    }
    float4* vrow = (float4*)(&vs[r][0]);
    vrow[c] = va; vrow[8+c] = vb; vrow[16+c] = vc4; vrow[24+c] = vd;
  }
  __syncthreads();   // ks / vs cross-wave visibility
  // QK^T: s[jj] = q[r] . k[4c+jj]
  float p0, p1, p2, p3;
  {
    float s[4];
    for (int jj = 0; jj < 4; jj++){
      int j = 4*c + jj; float acc = 0.f;
      for (int cc = 0; cc < 16; cc++) acc += qs[r][cc] * ks[j][cc];
      s[jj] = acc;
    }
    // row softmax across the 8-lane subgroup (all lanes active)
    float m = fmaxf(fmaxf(s[0], s[1]), fmaxf(s[2], s[3]));
    m = fmaxf(m, __shfl_xor(m, 1));
    m = fmaxf(m, __shfl_xor(m, 2));
    m = fmaxf(m, __shfl_xor(m, 4));
    float e0 = expf(s[0]-m), e1 = expf(s[1]-m), e2 = expf(s[2]-m), e3 = expf(s[3]-m);
    float sum = ((e0 + e1) + (e2 + e3));
    sum += __shfl_xor(sum, 1);
    sum += __shfl_xor(sum, 2);
    sum += __shfl_xor(sum, 4);
    float inv = 1.0f / sum;
    p0 = e0*inv; p1 = e1*inv; p2 = e2*inv; p3 = e3*inv;
    at[r][4*c+0] = p0; at[r][4*c+1] = p1; at[r][4*c+2] = p2; at[r][4*c+3] = p3;
  }
  // PV + gamma*.+x residual (at row r is wave-local; vs synced above)
  {
    float4 a0 = {0,0,0,0}, a1 = {0,0,0,0}, a2 = {0,0,0,0}, a3 = {0,0,0,0};
    for (int j = 0; j < 32; j++){
      float a = at[r][j];
      const float4* vrow = (const float4*)(&vs[j][0]);
      float4 w0 = vrow[c], w1 = vrow[8+c], w2 = vrow[16+c], w3 = vrow[24+c];
      a0.x += a*w0.x; a0.y += a*w0.y; a0.z += a*w0.z; a0.w += a*w0.w;
      a1.x += a*w1.x; a1.y += a*w1.y; a1.z += a*w1.z; a1.w += a*w1.w;
      a2.x += a*w2.x; a2.y += a*w2.y; a2.z += a*w2.z; a2.w += a*w2.w;
      a3.x += a*w3.x; a3.y += a*w3.y; a3.z += a*w3.z; a3.w += a*w3.w;
    }
    const float gmn = nsa_g[0];
    float* dst = g_dsa + ((size_t)g*32 + r)*256;
    float4 x0 = *(const float4*)(&xs[r][ 0+4*c]);
    float4 x1 = *(const float4*)(&xs[r][32+4*c]);
    float4 x2 = *(const float4*)(&xs[r][64+4*c]);
    float4 x3 = *(const float4*)(&xs[r][96+4*c]);
    float4 o0 = {gmn*a0.x+x0.x, gmn*a0.y+x0.y, gmn*a0.z+x0.z, gmn*a0.w+x0.w};
    float4 o1 = {gmn*a1.x+x1.x, gmn*a1.y+x1.y, gmn*a1.z+x1.z, gmn*a1.w+x1.w};
    float4 o2 = {gmn*a2.x+x2.x, gmn*a2.y+x2.y, gmn*a2.z+x2.z, gmn*a2.w+x2.w};
    float4 o3 = {gmn*a3.x+x3.x, gmn*a3.y+x3.y, gmn*a3.z+x3.z, gmn*a3.w+x3.w};
    *(float4*)(dst +  0 + 4*c) = o0;
    *(float4*)(dst + 32 + 4*c) = o1;
    *(float4*)(dst + 64 + 4*c) = o2;
    *(float4*)(dst + 96 + 4*c) = o3;
  }
}

// ---------------------------------------------------------------- cat MLP + shortcut + maxpool -> out
// Round-3 structure (measured best: 530us). 256 threads, separate hs buffer. FROZEN.
__global__ __launch_bounds__(256) void k_mlp(const float* __restrict__ points,
    const float* __restrict__ w1, const float* __restrict__ b1, const float* __restrict__ bn1,
    const float* __restrict__ w2, const float* __restrict__ b2, const float* __restrict__ bn2,
    const float* __restrict__ wsc, const float* __restrict__ bsc, const float* __restrict__ bnsc,
    float* __restrict__ out){
  const int g = blockIdx.y*512 + blockIdx.x;
  const int t = threadIdx.x, b = g >> 9;
  __shared__ float ds[32][260];
  __shared__ float hs[32][260];
  __shared__ float ps[32][68];
  __shared__ float a1s[256], d1s[256];
  __shared__ float red[256];
  for (int i = t; i < 2048; i += 256){
    int r = i >> 6, c = (i & 63) * 4;
    *(float4*)(&ds[r][c]) = *(const float4*)(g_dsa + ((size_t)g*32 + r)*256 + c);
  }
  for (int i = t; i < 512; i += 256){
    int r = i >> 4, c = (i & 15) * 4;
    int idx = g_knn_idx[g*32 + r];
    *(float4*)(&ps[r][c]) = *(const float4*)(points + ((size_t)b*NPTS + idx)*64 + c);
  }
  {
    float gg2 = bn1[t], be = bn1[256+t], m = bn1[512+t], v = bn1[768+t];
    float a = gg2 * rsqrtf(v + 1e-5f);
    a1s[t] = a; d1s[t] = b1[t]*a + (be - m*a);
  }
  __syncthreads();
  // C1: h = relu(bn1(dsa @ W1 + b1))
  {
    const int kg = t >> 6, c0 = (t & 63) * 4;
    float acc[8][4] = {};
    for (int j = 0; j < 256; j += 4){
      float wvv[4][4];
      for (int jj = 0; jj < 4; jj++){
        float4 wrow = *(const float4*)(w1 + (j+jj)*256 + c0);
        wvv[jj][0] = wrow.x; wvv[jj][1] = wrow.y; wvv[jj][2] = wrow.z; wvv[jj][3] = wrow.w;
      }
      for (int r = 0; r < 8; r++){
        const float4 d4 = *(const float4*)(&ds[kg*8+r][j]);
        const float dr[4] = {d4.x, d4.y, d4.z, d4.w};
        for (int jj = 0; jj < 4; jj++)
          for (int i = 0; i < 4; i++) acc[r][i] += dr[jj]*wvv[jj][i];
      }
    }
    for (int r = 0; r < 8; r++){
      float4 o;
      o.x = fmaxf(acc[r][0]*a1s[c0+0] + d1s[c0+0], 0.f);
      o.y = fmaxf(acc[r][1]*a1s[c0+1] + d1s[c0+1], 0.f);
      o.z = fmaxf(acc[r][2]*a1s[c0+2] + d1s[c0+2], 0.f);
      o.w = fmaxf(acc[r][3]*a1s[c0+3] + d1s[c0+3], 0.f);
      *(float4*)(&hs[kg*8+r][c0]) = o;
    }
  }
  __syncthreads();
  // C2: layer 2 + shortcut + relu + max over k
  {
    const int c = t & 127, kh = t >> 7;
    float g2 = bn2[c], be2 = bn2[128+c], m2 = bn2[256+c], v2 = bn2[384+c];
    float a2 = g2 * rsqrtf(v2 + 1e-5f);
    float d2v = b2[c]*a2 + (be2 - m2*a2);
    float gsc = bnsc[c], besc = bnsc[128+c], msc = bnsc[256+c], vsc = bnsc[384+c];
    float asc = gsc * rsqrtf(vsc + 1e-5f);
    float dscv = bsc[c]*asc + (besc - msc*asc);
    float accm[16] = {};
    for (int j = 0; j < 256; j += 4){
      float w0 = w2[j*128+c], w1v = w2[(j+1)*128+c];
      float w2v = w2[(j+2)*128+c], w3 = w2[(j+3)*128+c];
      for (int r = 0; r < 16; r++){
        const float4 h4 = *(const float4*)(&hs[kh*16+r][j]);
        accm[r] += h4.x*w0; accm[r] += h4.y*w1v; accm[r] += h4.z*w2v; accm[r] += h4.w*w3;
      }
    }
    float accs[16] = {};
    for (int j = 0; j < 64; j += 4){
      float w0 = wsc[j*128+c], w1v = wsc[(j+1)*128+c];
      float w2v = wsc[(j+2)*128+c], w3 = wsc[(j+3)*128+c];
      for (int r = 0; r < 16; r++){
        const float4 p4 = *(const float4*)(&ps[kh*16+r][j]);
        accs[r] += p4.x*w0; accs[r] += p4.y*w1v; accs[r] += p4.z*w2v; accs[r] += p4.w*w3;
      }
    }
    float mx = -1e30f;
    for (int r = 0; r < 16; r++){
      float mainv = accm[r]*a2 + d2v;
      float scv = fmaxf(accs[r]*asc + dscv, 0.f);
      mx = fmaxf(mx, fmaxf(mainv + scv, 0.f));
    }
    red[t] = mx;
  }
  __syncthreads();
  if (t < 128){
    float m = fmaxf(red[t], red[t+128]);
    out[12288 + (size_t)g*128 + t] = m;
  }
}

// ----------------------------------------------------------------
extern "C" void kernel_launch(void* const* d_in, const int* in_sizes, int n_in,
                              void* d_out, int out_size, void* d_ws, size_t ws_size,
                              hipStream_t stream){
  (void)in_sizes; (void)n_in; (void)d_ws; (void)ws_size; (void)out_size;
  const float* xyz      = (const float*)d_in[0];
  const float* points   = (const float*)d_in[1];
  const int*   fstart   = (const int*)  d_in[2];
  const float* pos_w1   = (const float*)d_in[3];
  const float* pos_b1   = (const float*)d_in[4];
  const float* pos_bn1  = (const float*)d_in[5];
  const float* pos_w2   = (const float*)d_in[6];
  const float* pos_b2   = (const float*)d_in[7];
  const float* pos_bn2  = (const float*)d_in[8];
  const float* nsa_wq   = (const float*)d_in[9];
  const float* nsa_bq   = (const float*)d_in[10];
  const float* nsa_wk   = (const float*)d_in[11];
  const float* nsa_bk   = (const float*)d_in[12];
  const float* nsa_wv   = (const float*)d_in[13];
  const float* nsa_bv   = (const float*)d_in[14];
  const float* nsa_g    = (const float*)d_in[15];
  const float* gam_g    = (const float*)d_in[16];
  const float* cat_w1   = (const float*)d_in[17];
  const float* cat_b1   = (const float*)d_in[18];
  const float* cat_bn1  = (const float*)d_in[19];
  const float* cat_w2   = (const float*)d_in[20];
  const float* cat_b2   = (const float*)d_in[21];
  const float* cat_bn2  = (const float*)d_in[22];
  const float* sc_w     = (const float*)d_in[23];
  const float* sc_b     = (const float*)d_in[24];
  const float* sc_bn    = (const float*)d_in[25];
  float* out = (float*)d_out;   // output is float32

  k_fps     <<<NB, 256, 0, stream>>>(xyz, fstart, out);
  k_knn     <<<NB*NS, 256, 0, stream>>>(xyz);
  k_posembed<<<512, 256, 0, stream>>>(xyz, pos_w1, pos_b1, pos_bn1, pos_w2, pos_b2, pos_bn2);
  k_gram    <<<dim3(36, NB, 4), 256, 0, stream>>>(points);
  k_gsm     <<<NB*NS, 256, 0, stream>>>();
  k_grp     <<<dim3(512, NB), 256, 0, stream>>>(points, gam_g);
  k_nsa     <<<dim3(512, NB), 256, 0, stream>>>(points, nsa_wq, nsa_bq, nsa_wk, nsa_bk,
                                                nsa_wv, nsa_bv, nsa_g);
  k_mlp     <<<dim3(512, NB), 256, 0, stream>>>(points, cat_w1, cat_b1, cat_bn1,
                                                cat_w2, cat_b2, cat_bn2,
                                                sc_w, sc_b, sc_bn, out);
}

// Round 12
// 1625.821 us; speedup vs baseline: 3.2053x; 1.0333x over previous
//
#include <hip/hip_runtime.h>
#include <stdint.h>
#include <float.h>

typedef unsigned int uint;

#define NB 8
#define NPTS 4096
#define NS 512
#define NKN 32

// ---- static device scratch (~210 MB, allocated at module load; fully rewritten each call)
__device__ int   g_fps_idx[NB*NS];
__device__ int   g_knn_idx[NB*NS*NKN];
__device__ float g_posb   [(size_t)NB*NS*NKN*64];    //  33.5 MB
__device__ float g_ga     [(size_t)NB*NS*NS];        //   8.4 MB
__device__ float g_gp     [(size_t)4*NB*NS*NS];      //  33.5 MB gram K-chunk partials
__device__ float g_dsa    [(size_t)NB*NS*NKN*256];   // 134 MB  [group*32+k][256] = [nei|grp]

__device__ __forceinline__ unsigned long long shfl_down_u64(unsigned long long v, int off){
  int lo = __shfl_down((int)(unsigned)v, off);
  int hi = __shfl_down((int)(unsigned)(v >> 32), off);
  return ((unsigned long long)(unsigned)hi << 32) | (unsigned)lo;
}
__device__ __forceinline__ unsigned long long u64max(unsigned long long a, unsigned long long b){
  return a > b ? a : b;
}
__device__ __forceinline__ unsigned long long u64min(unsigned long long a, unsigned long long b){
  return a < b ? a : b;
}
__device__ __forceinline__ void ldf8(const float* p, float* d){
  float4 a = *(const float4*)p, b = *(const float4*)(p+4);
  d[0]=a.x; d[1]=a.y; d[2]=a.z; d[3]=a.w; d[4]=b.x; d[5]=b.y; d[6]=b.z; d[7]=b.w;
}
// robust start read: int32 (start[b]) vs int64 (start[2b]; high words zero since values<4096)
__device__ __forceinline__ int read_start(const int* __restrict__ start, int b){
  int w1 = start[1], w3 = start[3], w5 = start[5], w7 = start[7];
  bool is64 = ((w1 | w3 | w5 | w7) == 0);
  int v = is64 ? start[2*b] : start[b];
  return v & (NPTS - 1);
}

// flat column order: n = k*128 + d, d<64 -> posb, d>=64 -> points gather
__device__ __forceinline__ void load_flat8(const float* __restrict__ points,
                                           int b, int row, int n, float* d){
  const int k = n >> 7, col = n & 63;
  if (n & 64){
    const int idx = g_knn_idx[((b << 9) + row)*32 + k];
    ldf8(points + (((size_t)b << 12) + idx)*64 + col, d);
  } else {
    ldf8(g_posb + (((size_t)((b << 9) + row))*32 + k)*64 + col, d);
  }
}
__device__ __forceinline__ float4 load_flat4(const float* __restrict__ points,
                                             int b, int row, int n){
  const int k = n >> 7, d = n & 127;
  if (d & 64){
    const int idx = g_knn_idx[((b << 9) + row)*32 + k];
    return *(const float4*)(points + (((size_t)b << 12) + idx)*64 + (d & 63));
  } else {
    return *(const float4*)(g_posb + (((size_t)((b << 9) + row))*32 + k)*64 + d);
  }
}
// reorganized order for Gram only: kc in [0,2048) pos (k-major), [2048,4096) pts
__device__ __forceinline__ void load_gram8(const float* __restrict__ points,
                                           int b, int row, int kc, float* d){
  if (kc < 2048){
    ldf8(g_posb + ((size_t)((b << 9) + row))*2048 + kc, d);
  } else {
    const int kc2 = kc - 2048, kg = kc2 >> 6, col = kc2 & 63;
    const int idx = g_knn_idx[((b << 9) + row)*32 + kg];
    ldf8(points + (((size_t)b << 12) + idx)*64 + col, d);
  }
}

// ---------------------------------------------------------------- FPS (f32 running-max + packed-key shuffle, 256 thr)
__global__ __launch_bounds__(256) void k_fps(const float* __restrict__ xyz,
                                             const int* __restrict__ start,
                                             float* __restrict__ center_out){
#pragma clang fp contract(off)
  const int b = blockIdx.x, tid = threadIdx.x;
  const float* X = xyz + (size_t)b * NPTS * 3;
  __shared__ float sx[NPTS], sy[NPTS], sz[NPTS];
  for (int p = tid; p < NPTS; p += 256){
    sx[p] = X[3*p]; sy[p] = X[3*p+1]; sz[p] = X[3*p+2];
  }
  __shared__ int s_start0;
  if (tid == 0) s_start0 = read_start(start, b);
  __syncthreads();
  float px[16], py[16], pz[16], dist[16];
  for (int i = 0; i < 16; i++){
    int p = tid*16 + i;
    px[i] = sx[p]; py[i] = sy[p]; pz[i] = sz[p];
    dist[i] = 1e10f;
  }
  __shared__ unsigned long long s_k[2][4];
  int cur = s_start0;
  for (int t = 0; t < NS; t++){
    if (tid == 0){
      g_fps_idx[b*NS + t] = cur;
      center_out[(size_t)(b*NS + t)*3 + 0] = sx[cur];
      center_out[(size_t)(b*NS + t)*3 + 1] = sy[cur];
      center_out[(size_t)(b*NS + t)*3 + 2] = sz[cur];
    }
    const float cx = sx[cur], cy = sy[cur], cz = sz[cur];
    float bv = -1.0f; int bi = 0;
#pragma unroll
    for (int i = 0; i < 16; i++){
      float dx = px[i]-cx, dy = py[i]-cy, dz = pz[i]-cz;
      float d = ((dx*dx) + (dy*dy)) + (dz*dz);
      dist[i] = fminf(dist[i], d);
      if (dist[i] > bv){ bv = dist[i]; bi = i; }   // strict >: keeps lower i (= lower idx)
    }
    unsigned long long bk = ((unsigned long long)__float_as_uint(bv) << 32)
                          | (unsigned)(NPTS-1 - (tid*16 + bi));
    { unsigned long long a = shfl_down_u64(bk,16), c = shfl_down_u64(bk,32), d = shfl_down_u64(bk,48);
      bk = u64max(u64max(bk,a), u64max(c,d)); }
    { unsigned long long a = shfl_down_u64(bk,4),  c = shfl_down_u64(bk,8),  d = shfl_down_u64(bk,12);
      bk = u64max(u64max(bk,a), u64max(c,d)); }
    { unsigned long long a = shfl_down_u64(bk,1),  c = shfl_down_u64(bk,2),  d = shfl_down_u64(bk,3);
      bk = u64max(u64max(bk,a), u64max(c,d)); }
    const int par = t & 1;
    if ((tid & 63) == 0) s_k[par][tid>>6] = bk;
    __syncthreads();
    unsigned long long m = u64max(u64max(s_k[par][0], s_k[par][1]),
                                  u64max(s_k[par][2], s_k[par][3]));
    cur = NPTS-1 - (int)(unsigned)m;
  }
}

// ---------------------------------------------------------------- KNN top-32 + fused pos-embed MLP
// knn block g produces exactly the 32 (idx, d2) pairs posembed's rows g*32..+32
// consume -> fused: selection results kept in LDS, posembed tail fills knn's
// idle issue slots (VALUBusy was ~24%), g_knn_d2 global round-trip eliminated.
// Micro-opts: float4 preload of the thread's 48 contiguous xyz floats; running-min
// masked scan replaces build+tree (same qualifying-set min -> bit-exact).
__global__ __launch_bounds__(256) void k_knn(const float* __restrict__ xyz,
    const float* __restrict__ w1, const float* __restrict__ b1, const float* __restrict__ bn1,
    const float* __restrict__ w2, const float* __restrict__ b2, const float* __restrict__ bn2){
#pragma clang fp contract(off)
  const int g = blockIdx.x;            // b*512 + s
  const int b = g >> 9;
  const int tid = threadIdx.x;
  const float* X = xyz + (size_t)b * NPTS * 3;
  __shared__ float w1s[320], a1s[32], d1s[32], w2s[2048], a2s[64], d2s[64];
  __shared__ int   s_ni[32];
  __shared__ float s_nd[32];
  __shared__ unsigned long long s_w[2][4];
  for (int i = tid; i < 320; i += 256) w1s[i] = w1[i];
  for (int i = tid; i < 2048; i += 256) w2s[i] = w2[i];
  if (tid < 32){
    float gg = bn1[tid], be = bn1[32+tid], m = bn1[64+tid], v = bn1[96+tid];
    float a = gg * rsqrtf(v + 1e-5f);
    a1s[tid] = a; d1s[tid] = b1[tid]*a + (be - m*a);
  }
  if (tid < 64){
    float gg = bn2[tid], be = bn2[64+tid], m = bn2[128+tid], v = bn2[192+tid];
    float a = gg * rsqrtf(v + 1e-5f);
    a2s[tid] = a; d2s[tid] = b2[tid]*a + (be - m*a);
  }
  const int cidx = g_fps_idx[g];
  const float cx = X[3*cidx], cy = X[3*cidx+1], cz = X[3*cidx+2];
  const float cs = ((cx*cx) + (cy*cy)) + (cz*cz);
  float xl[48];
  {
    const float4* Xp = (const float4*)(X + tid*48);
#pragma unroll
    for (int q = 0; q < 12; q++){
      float4 v = Xp[q];
      xl[q*4+0]=v.x; xl[q*4+1]=v.y; xl[q*4+2]=v.z; xl[q*4+3]=v.w;
    }
  }
  unsigned long long kl[16];
#pragma unroll
  for (int i = 0; i < 16; i++){
    int p = tid*16 + i;
    float x = xl[3*i], y = xl[3*i+1], z = xl[3*i+2];
    float xs2 = ((x*x) + (y*y)) + (z*z);
    float dt  = ((cx*x) + (cy*y)) + (cz*z);
    float d   = (cs + xs2) - 2.0f*dt;
    unsigned bits = __float_as_uint(d);
    unsigned mono = (bits & 0x80000000u) ? ~bits : (bits ^ 0x80000000u);
    kl[i] = ((unsigned long long)mono << 32) | (unsigned)p;
  }
  unsigned long long last = 0;
  for (int sel = 0; sel < NKN; sel++){
    unsigned long long bk = 0xFFFFFFFFFFFFFFFFULL;
#pragma unroll
    for (int i = 0; i < 16; i++){
      unsigned long long k = kl[i];
      if (k > last && k < bk) bk = k;    // running min over qualifying set
    }
    { unsigned long long a = shfl_down_u64(bk,16), c = shfl_down_u64(bk,32), d = shfl_down_u64(bk,48);
      bk = u64min(u64min(bk,a), u64min(c,d)); }
    { unsigned long long a = shfl_down_u64(bk,4),  c = shfl_down_u64(bk,8),  d = shfl_down_u64(bk,12);
      bk = u64min(u64min(bk,a), u64min(c,d)); }
    { unsigned long long a = shfl_down_u64(bk,1),  c = shfl_down_u64(bk,2),  d = shfl_down_u64(bk,3);
      bk = u64min(u64min(bk,a), u64min(c,d)); }
    const int par = sel & 1;
    if ((tid & 63) == 0) s_w[par][tid>>6] = bk;
    __syncthreads();
    unsigned long long m = u64min(u64min(s_w[par][0], s_w[par][1]),
                                  u64min(s_w[par][2], s_w[par][3]));
    last = m;
    if (tid == 0){
      int ni = (int)(unsigned)m;
      g_knn_idx[g*NKN + sel] = ni;
      s_ni[sel] = ni;
      unsigned hm = (unsigned)(m >> 32);
      unsigned bits = (hm & 0x80000000u) ? (hm ^ 0x80000000u) : ~hm;
      s_nd[sel] = __uint_as_float(bits);
    }
  }
  __syncthreads();    // publish sel=31 results + weight staging already fenced
  // ---- fused pos-embed: 8 threads per row, identical formulas & order -> bit-exact
  {
    const int r = tid >> 3, c8 = (tid & 7) * 8;
    const int ni = s_ni[r];
    float n0 = X[3*ni], n1 = X[3*ni+1], n2 = X[3*ni+2];
    float feat[10] = {cx,cy,cz, n0,n1,n2, n0-cx,n1-cy,n2-cz, s_nd[r]};
    float h[32];
    for (int o = 0; o < 32; o++){
      float acc = 0.f;
      for (int j = 0; j < 10; j++) acc += feat[j]*w1s[j*32+o];
      h[o] = fmaxf(acc*a1s[o] + d1s[o], 0.f);
    }
    float o8[8];
#pragma unroll
    for (int oo = 0; oo < 8; oo++){
      int o = c8 + oo;
      float acc = 0.f;
      for (int j = 0; j < 32; j++) acc += h[j]*w2s[j*64+o];
      o8[oo] = fmaxf(acc*a2s[o] + d2s[o], 0.f);
    }
    float* xr = g_posb + ((size_t)g*32 + r)*64;
    float4 v0 = {o8[0], o8[1], o8[2], o8[3]};
    float4 v1 = {o8[4], o8[5], o8[6], o8[7]};
    *(float4*)(xr + c8)     = v0;
    *(float4*)(xr + c8 + 4) = v1;
  }
}

// ---------------------------------------------------------------- Gram partials (K-split x4, symmetric)
__global__ __launch_bounds__(256) void k_gram(const float* __restrict__ points){
  const int b = blockIdx.y, ch = blockIdx.z;
  int ti = 0, rem = blockIdx.x;
  while (rem >= 8 - ti){ rem -= 8 - ti; ti++; }
  const int tj = ti + rem;
  const int i0 = ti * 64, j0 = tj * 64;
  __shared__ float As[32][68];
  __shared__ float Bs[32][68];
  const int t = threadIdx.x, tx = t & 15, ty = t >> 4;
  float acc[4][4] = {};
  const int kbeg = ch * 1024, kend = kbeg + 1024;
  for (int k0 = kbeg; k0 < kend; k0 += 32){
    {
      int r = t >> 2, kk = (t & 3) * 8;
      float ta[8], tb[8];
      load_gram8(points, b, i0+r, k0+kk, ta);
      load_gram8(points, b, j0+r, k0+kk, tb);
      for (int jj = 0; jj < 8; jj++){
        int k = kk + jj;
        int c = (r + (k & 24)) & 63;   // rotated column, conflict-free store
        As[k][c] = ta[jj]; Bs[k][c] = tb[jj];
      }
    }
    __syncthreads();
    for (int kk = 0; kk < 32; kk++){
      const int rot = kk & 24;
      const float4 a4 = *(const float4*)(&As[kk][(ty*4 + rot) & 63]);
      const float4 b4 = *(const float4*)(&Bs[kk][(tx*4 + rot) & 63]);
      const float ar[4] = {a4.x,a4.y,a4.z,a4.w};
      const float br[4] = {b4.x,b4.y,b4.z,b4.w};
      for (int ia = 0; ia < 4; ia++)
        for (int ib = 0; ib < 4; ib++) acc[ia][ib] += ar[ia]*br[ib];
    }
    __syncthreads();
  }
  float* C = g_gp + ((size_t)(ch*NB + b)) * NS * NS;
  for (int ia = 0; ia < 4; ia++){
    float4 o = {acc[ia][0], acc[ia][1], acc[ia][2], acc[ia][3]};
    *(float4*)(C + (size_t)(i0+ty*4+ia)*NS + j0 + tx*4) = o;
  }
  if (ti != tj){
    for (int ib = 0; ib < 4; ib++){
      float4 o = {acc[0][ib], acc[1][ib], acc[2][ib], acc[3][ib]};
      *(float4*)(C + (size_t)(j0+tx*4+ib)*NS + i0 + ty*4) = o;
    }
  }
}

// ---------------------------------------------------------------- fused gram-reduce + row softmax -> g_ga
__global__ __launch_bounds__(256) void k_gsm(){
  const size_t N = (size_t)NB * NS * NS;
  const size_t base = (size_t)blockIdx.x * NS;
  const int t = threadIdx.x;
  float v0, v1;
  {
    float a0 = g_gp[base + t],       b0 = g_gp[N + base + t];
    float c0 = g_gp[2*N + base + t], d0 = g_gp[3*N + base + t];
    v0 = ((a0 + b0) + c0) + d0;
    float a1 = g_gp[base + t + 256],       b1 = g_gp[N + base + t + 256];
    float c1 = g_gp[2*N + base + t + 256], d1 = g_gp[3*N + base + t + 256];
    v1 = ((a1 + b1) + c1) + d1;
  }
  __shared__ float sm[4], ssum[4];
  float m = fmaxf(v0, v1);
  for (int off = 32; off; off >>= 1) m = fmaxf(m, __shfl_down(m, off));
  if ((t & 63) == 0) sm[t>>6] = m;
  __syncthreads();
  float mm = fmaxf(fmaxf(sm[0], sm[1]), fmaxf(sm[2], sm[3]));
  float e0 = expf(v0 - mm), e1 = expf(v1 - mm);
  float s = e0 + e1;
  for (int off = 32; off; off >>= 1) s += __shfl_down(s, off);
  if ((t & 63) == 0) ssum[t>>6] = s;
  __syncthreads();
  float inv = 1.0f / (ssum[0]+ssum[1]+ssum[2]+ssum[3]);
  g_ga[base + t] = e0*inv;
  g_ga[base + t + 256] = e1*inv;
}

// ---------------------------------------------------------------- grp: ga @ flat, fused gamma*+x -> g_dsa[...,128:256]
__global__ __launch_bounds__(256) void k_grp(const float* __restrict__ points,
                                             const float* __restrict__ gam_g){
  const int b = blockIdx.y;
  const int s0 = (blockIdx.x >> 6) * 64, n0 = (blockIdx.x & 63) * 64;
  const float* G = g_ga + (size_t)b * NS * NS;
  __shared__ float As[32][68];
  __shared__ float Bs[32][68];
  const int t = threadIdx.x, tx = t & 15, ty = t >> 4;
  float acc[4][4] = {};
  for (int k0 = 0; k0 < NS; k0 += 32){
    {
      int r = t >> 2, kk = (t & 3) * 8;
      const float* pa = G + (size_t)(s0+r)*NS + k0 + kk;
      float4 v0 = *(const float4*)pa, v1 = *(const float4*)(pa+4);
      const float va[8] = {v0.x,v0.y,v0.z,v0.w,v1.x,v1.y,v1.z,v1.w};
      for (int jj = 0; jj < 8; jj++){
        int k = kk + jj;
        As[k][(r + (k & 24)) & 63] = va[jj];   // rotated column, conflict-free store
      }
      int k2 = t >> 3, c = (t & 7) * 8;
      float tb[8];
      load_flat8(points, b, k0+k2, n0+c, tb);
      float4 w0 = {tb[0],tb[1],tb[2],tb[3]}, w1 = {tb[4],tb[5],tb[6],tb[7]};
      *(float4*)(&Bs[k2][c])   = w0;
      *(float4*)(&Bs[k2][c+4]) = w1;
    }
    __syncthreads();
    for (int kk = 0; kk < 32; kk++){
      const float4 a4 = *(const float4*)(&As[kk][(ty*4 + (kk & 24)) & 63]);
      const float4 b4 = *(const float4*)(&Bs[kk][tx*4]);
      const float ar[4] = {a4.x,a4.y,a4.z,a4.w};
      const float br[4] = {b4.x,b4.y,b4.z,b4.w};
      for (int ia = 0; ia < 4; ia++)
        for (int ib = 0; ib < 4; ib++) acc[ia][ib] += ar[ia]*br[ib];
    }
    __syncthreads();
  }
  const float gmg = gam_g[0];
  const int n = n0 + tx*4;
  const int kq = n >> 7, dq = n & 127;
  for (int ia = 0; ia < 4; ia++){
    int s = s0 + ty*4 + ia;
    float4 xv = load_flat4(points, b, s, n);
    float4 o = {gmg*acc[ia][0]+xv.x, gmg*acc[ia][1]+xv.y,
                gmg*acc[ia][2]+xv.z, gmg*acc[ia][3]+xv.w};
    *(float4*)(g_dsa + ((size_t)((b*NS + s)*32 + kq))*256 + 128 + dq) = o;
  }
}

// ---------------------------------------------------------------- NSA: Q/K/V + softmax + PV -> g_dsa[...,0:128]
// Weight LDS staging (kills 32x per-block weight re-streaming through L2) with
// loop-unroll pinning to prevent register spill (round-8 lesson).
__global__ __launch_bounds__(256) void k_nsa(const float* __restrict__ points,
    const float* __restrict__ wq, const float* __restrict__ bq,
    const float* __restrict__ wk, const float* __restrict__ bk,
    const float* __restrict__ wv, const float* __restrict__ bv_,
    const float* __restrict__ nsa_g){
  const int g = blockIdx.y*512 + blockIdx.x;
  const int t = threadIdx.x, b = g >> 9;
  const int r = t >> 3, c = t & 7;
  __shared__ float xs[32][132];
  __shared__ float vs[32][132];          // float4 view: row stride 33
  __shared__ float qs[32][17], ks[32][17];
  __shared__ float at[32][33];
  __shared__ float wqs[2048];            // 128x16
  __shared__ float wks[2048];            // 128x16
  __shared__ float wvs[4096];            // 32x128 tile (reused 4x)
  // stage x row r (8 lanes of subgroup r cover the row) + wq/wk
  {
    float tmp[8];
    ldf8(g_posb + ((size_t)g*32 + r)*64 + c*8, tmp);
    for (int j = 0; j < 8; j++) xs[r][c*8+j] = tmp[j];
    int idx = g_knn_idx[g*32 + r];
    ldf8(points + ((size_t)b*NPTS + idx)*64 + c*8, tmp);
    for (int j = 0; j < 8; j++) xs[r][64+c*8+j] = tmp[j];
  }
  for (int i = t; i < 512; i += 256){
    ((float4*)wqs)[i] = ((const float4*)wq)[i];
    ((float4*)wks)[i] = ((const float4*)wk)[i];
  }
  __syncthreads();
  // Q/K projections from LDS (thread computes q[r][c], q[r][c+8], k[r][c], k[r][c+8])
  {
    float aq0 = bq[c], aq1 = bq[c+8], ak0 = bk[c], ak1 = bk[c+8];
#pragma unroll 8
    for (int j = 0; j < 128; j++){
      float xv = xs[r][j];
      aq0 += xv * wqs[j*16+c];
      aq1 += xv * wqs[j*16+c+8];
      ak0 += xv * wks[j*16+c];
      ak1 += xv * wks[j*16+c+8];
    }
    qs[r][c] = aq0; qs[r][c+8] = aq1; ks[r][c] = ak0; ks[r][c+8] = ak1;
  }
  // V projection, channels d = 32w + 4c + ii; wv streamed through LDS in 32-row tiles
  {
    const float4* bv4 = (const float4*)bv_;
    float4 va = bv4[c], vb = bv4[8+c], vc4 = bv4[16+c], vd = bv4[24+c];
#pragma unroll 1
    for (int t4 = 0; t4 < 4; t4++){
      if (t4) __syncthreads();           // prior tile's reads complete before overwrite
      for (int i = t; i < 1024; i += 256)
        ((float4*)wvs)[i] = ((const float4*)wv)[(size_t)t4*1024 + i];
      __syncthreads();
#pragma unroll 4
      for (int jl = 0; jl < 32; jl++){
        float xv = xs[r][t4*32 + jl];
        const float4* row = (const float4*)(wvs + jl*128);
        float4 w0 = row[c], w1 = row[8+c], w2 = row[16+c], w3 = row[24+c];
        va.x += xv*w0.x;  va.y += xv*w0.y;  va.z += xv*w0.z;  va.w += xv*w0.w;
        vb.x += xv*w1.x;  vb.y += xv*w1.y;  vb.z += xv*w1.z;  vb.w += xv*w1.w;
        vc4.x += xv*w2.x; vc4.y += xv*w2.y; vc4.z += xv*w2.z; vc4.w += xv*w2.w;
        vd.x += xv*w3.x;  vd.y += xv*w3.y;  vd.z += xv*w3.z;  vd.w += xv*w3.w;
      }
    }
    float4* vrow = (float4*)(&vs[r][0]);
    vrow[c] = va; vrow[8+c] = vb; vrow[16+c] = vc4; vrow[24+c] = vd;
  }
  __syncthreads();   // ks / vs cross-wave visibility
  // QK^T: s[jj] = q[r] . k[4c+jj]
  float p0, p1, p2, p3;
  {
    float s[4];
    for (int jj = 0; jj < 4; jj++){
      int j = 4*c + jj; float acc = 0.f;
      for (int cc = 0; cc < 16; cc++) acc += qs[r][cc] * ks[j][cc];
      s[jj] = acc;
    }
    // row softmax across the 8-lane subgroup (all lanes active)
    float m = fmaxf(fmaxf(s[0], s[1]), fmaxf(s[2], s[3]));
    m = fmaxf(m, __shfl_xor(m, 1));
    m = fmaxf(m, __shfl_xor(m, 2));
    m = fmaxf(m, __shfl_xor(m, 4));
    float e0 = expf(s[0]-m), e1 = expf(s[1]-m), e2 = expf(s[2]-m), e3 = expf(s[3]-m);
    float sum = ((e0 + e1) + (e2 + e3));
    sum += __shfl_xor(sum, 1);
    sum += __shfl_xor(sum, 2);
    sum += __shfl_xor(sum, 4);
    float inv = 1.0f / sum;
    p0 = e0*inv; p1 = e1*inv; p2 = e2*inv; p3 = e3*inv;
    at[r][4*c+0] = p0; at[r][4*c+1] = p1; at[r][4*c+2] = p2; at[r][4*c+3] = p3;
  }
  // PV + gamma*.+x residual (at row r is wave-local; vs synced above)
  {
    float4 a0 = {0,0,0,0}, a1 = {0,0,0,0}, a2 = {0,0,0,0}, a3 = {0,0,0,0};
    for (int j = 0; j < 32; j++){
      float a = at[r][j];
      const float4* vrow = (const float4*)(&vs[j][0]);
      float4 w0 = vrow[c], w1 = vrow[8+c], w2 = vrow[16+c], w3 = vrow[24+c];
      a0.x += a*w0.x; a0.y += a*w0.y; a0.z += a*w0.z; a0.w += a*w0.w;
      a1.x += a*w1.x; a1.y += a*w1.y; a1.z += a*w1.z; a1.w += a*w1.w;
      a2.x += a*w2.x; a2.y += a*w2.y; a2.z += a*w2.z; a2.w += a*w2.w;
      a3.x += a*w3.x; a3.y += a*w3.y; a3.z += a*w3.z; a3.w += a*w3.w;
    }
    const float gmn = nsa_g[0];
    float* dst = g_dsa + ((size_t)g*32 + r)*256;
    float4 x0 = *(const float4*)(&xs[r][ 0+4*c]);
    float4 x1 = *(const float4*)(&xs[r][32+4*c]);
    float4 x2 = *(const float4*)(&xs[r][64+4*c]);
    float4 x3 = *(const float4*)(&xs[r][96+4*c]);
    float4 o0 = {gmn*a0.x+x0.x, gmn*a0.y+x0.y, gmn*a0.z+x0.z, gmn*a0.w+x0.w};
    float4 o1 = {gmn*a1.x+x1.x, gmn*a1.y+x1.y, gmn*a1.z+x1.z, gmn*a1.w+x1.w};
    float4 o2 = {gmn*a2.x+x2.x, gmn*a2.y+x2.y, gmn*a2.z+x2.z, gmn*a2.w+x2.w};
    float4 o3 = {gmn*a3.x+x3.x, gmn*a3.y+x3.y, gmn*a3.z+x3.z, gmn*a3.w+x3.w};
    *(float4*)(dst +  0 + 4*c) = o0;
    *(float4*)(dst + 32 + 4*c) = o1;
    *(float4*)(dst + 64 + 4*c) = o2;
    *(float4*)(dst + 96 + 4*c) = o3;
  }
}

// ---------------------------------------------------------------- cat MLP + shortcut + maxpool -> out
// Round-3 structure (measured best: 530us). 256 threads, separate hs buffer. FROZEN.
__global__ __launch_bounds__(256) void k_mlp(const float* __restrict__ points,
    const float* __restrict__ w1, const float* __restrict__ b1, const float* __restrict__ bn1,
    const float* __restrict__ w2, const float* __restrict__ b2, const float* __restrict__ bn2,
    const float* __restrict__ wsc, const float* __restrict__ bsc, const float* __restrict__ bnsc,
    float* __restrict__ out){
  const int g = blockIdx.y*512 + blockIdx.x;
  const int t = threadIdx.x, b = g >> 9;
  __shared__ float ds[32][260];
  __shared__ float hs[32][260];
  __shared__ float ps[32][68];
  __shared__ float a1s[256], d1s[256];
  __shared__ float red[256];
  for (int i = t; i < 2048; i += 256){
    int r = i >> 6, c = (i & 63) * 4;
    *(float4*)(&ds[r][c]) = *(const float4*)(g_dsa + ((size_t)g*32 + r)*256 + c);
  }
  for (int i = t; i < 512; i += 256){
    int r = i >> 4, c = (i & 15) * 4;
    int idx = g_knn_idx[g*32 + r];
    *(float4*)(&ps[r][c]) = *(const float4*)(points + ((size_t)b*NPTS + idx)*64 + c);
  }
  {
    float gg2 = bn1[t], be = bn1[256+t], m = bn1[512+t], v = bn1[768+t];
    float a = gg2 * rsqrtf(v + 1e-5f);
    a1s[t] = a; d1s[t] = b1[t]*a + (be - m*a);
  }
  __syncthreads();
  // C1: h = relu(bn1(dsa @ W1 + b1))
  {
    const int kg = t >> 6, c0 = (t & 63) * 4;
    float acc[8][4] = {};
    for (int j = 0; j < 256; j += 4){
      float wvv[4][4];
      for (int jj = 0; jj < 4; jj++){
        float4 wrow = *(const float4*)(w1 + (j+jj)*256 + c0);
        wvv[jj][0] = wrow.x; wvv[jj][1] = wrow.y; wvv[jj][2] = wrow.z; wvv[jj][3] = wrow.w;
      }
      for (int r = 0; r < 8; r++){
        const float4 d4 = *(const float4*)(&ds[kg*8+r][j]);
        const float dr[4] = {d4.x, d4.y, d4.z, d4.w};
        for (int jj = 0; jj < 4; jj++)
          for (int i = 0; i < 4; i++) acc[r][i] += dr[jj]*wvv[jj][i];
      }
    }
    for (int r = 0; r < 8; r++){
      float4 o;
      o.x = fmaxf(acc[r][0]*a1s[c0+0] + d1s[c0+0], 0.f);
      o.y = fmaxf(acc[r][1]*a1s[c0+1] + d1s[c0+1], 0.f);
      o.z = fmaxf(acc[r][2]*a1s[c0+2] + d1s[c0+2], 0.f);
      o.w = fmaxf(acc[r][3]*a1s[c0+3] + d1s[c0+3], 0.f);
      *(float4*)(&hs[kg*8+r][c0]) = o;
    }
  }
  __syncthreads();
  // C2: layer 2 + shortcut + relu + max over k
  {
    const int c = t & 127, kh = t >> 7;
    float g2 = bn2[c], be2 = bn2[128+c], m2 = bn2[256+c], v2 = bn2[384+c];
    float a2 = g2 * rsqrtf(v2 + 1e-5f);
    float d2v = b2[c]*a2 + (be2 - m2*a2);
    float gsc = bnsc[c], besc = bnsc[128+c], msc = bnsc[256+c], vsc = bnsc[384+c];
    float asc = gsc * rsqrtf(vsc + 1e-5f);
    float dscv = bsc[c]*asc + (besc - msc*asc);
    float accm[16] = {};
    for (int j = 0; j < 256; j += 4){
      float w0 = w2[j*128+c], w1v = w2[(j+1)*128+c];
      float w2v = w2[(j+2)*128+c], w3 = w2[(j+3)*128+c];
      for (int r = 0; r < 16; r++){
        const float4 h4 = *(const float4*)(&hs[kh*16+r][j]);
        accm[r] += h4.x*w0; accm[r] += h4.y*w1v; accm[r] += h4.z*w2v; accm[r] += h4.w*w3;
      }
    }
    float accs[16] = {};
    for (int j = 0; j < 64; j += 4){
      float w0 = wsc[j*128+c], w1v = wsc[(j+1)*128+c];
      float w2v = wsc[(j+2)*128+c], w3 = wsc[(j+3)*128+c];
      for (int r = 0; r < 16; r++){
        const float4 p4 = *(const float4*)(&ps[kh*16+r][j]);
        accs[r] += p4.x*w0; accs[r] += p4.y*w1v; accs[r] += p4.z*w2v; accs[r] += p4.w*w3;
      }
    }
    float mx = -1e30f;
    for (int r = 0; r < 16; r++){
      float mainv = accm[r]*a2 + d2v;
      float scv = fmaxf(accs[r]*asc + dscv, 0.f);
      mx = fmaxf(mx, fmaxf(mainv + scv, 0.f));
    }
    red[t] = mx;
  }
  __syncthreads();
  if (t < 128){
    float m = fmaxf(red[t], red[t+128]);
    out[12288 + (size_t)g*128 + t] = m;
  }
}

// ----------------------------------------------------------------
extern "C" void kernel_launch(void* const* d_in, const int* in_sizes, int n_in,
                              void* d_out, int out_size, void* d_ws, size_t ws_size,
                              hipStream_t stream){
  (void)in_sizes; (void)n_in; (void)d_ws; (void)ws_size; (void)out_size;
  const float* xyz      = (const float*)d_in[0];
  const float* points   = (const float*)d_in[1];
  const int*   fstart   = (const int*)  d_in[2];
  const float* pos_w1   = (const float*)d_in[3];
  const float* pos_b1   = (const float*)d_in[4];
  const float* pos_bn1  = (const float*)d_in[5];
  const float* pos_w2   = (const float*)d_in[6];
  const float* pos_b2   = (const float*)d_in[7];
  const float* pos_bn2  = (const float*)d_in[8];
  const float* nsa_wq   = (const float*)d_in[9];
  const float* nsa_bq   = (const float*)d_in[10];
  const float* nsa_wk   = (const float*)d_in[11];
  const float* nsa_bk   = (const float*)d_in[12];
  const float* nsa_wv   = (const float*)d_in[13];
  const float* nsa_bv   = (const float*)d_in[14];
  const float* nsa_g    = (const float*)d_in[15];
  const float* gam_g    = (const float*)d_in[16];
  const float* cat_w1   = (const float*)d_in[17];
  const float* cat_b1   = (const float*)d_in[18];
  const float* cat_bn1  = (const float*)d_in[19];
  const float* cat_w2   = (const float*)d_in[20];
  const float* cat_b2   = (const float*)d_in[21];
  const float* cat_bn2  = (const float*)d_in[22];
  const float* sc_w     = (const float*)d_in[23];
  const float* sc_b     = (const float*)d_in[24];
  const float* sc_bn    = (const float*)d_in[25];
  float* out = (float*)d_out;   // output is float32

  k_fps     <<<NB, 256, 0, stream>>>(xyz, fstart, out);
  k_knn     <<<NB*NS, 256, 0, stream>>>(xyz, pos_w1, pos_b1, pos_bn1, pos_w2, pos_b2, pos_bn2);
  k_gram    <<<dim3(36, NB, 4), 256, 0, stream>>>(points);
  k_gsm     <<<NB*NS, 256, 0, stream>>>();
  k_grp     <<<dim3(512, NB), 256, 0, stream>>>(points, gam_g);
  k_nsa     <<<dim3(512, NB), 256, 0, stream>>>(points, nsa_wq, nsa_bq, nsa_wk, nsa_bk,
                                                nsa_wv, nsa_bv, nsa_g);
  k_mlp     <<<dim3(512, NB), 256, 0, stream>>>(points, cat_w1, cat_b1, cat_bn1,
                                                cat_w2, cat_b2, cat_bn2,
                                                sc_w, sc_b, sc_bn, out);
}